// Round 3
// baseline (664.316 us; speedup 1.0000x reference)
//
#include <hip/hip_runtime.h>
#include <stdint.h>

using bf16x8 = __attribute__((ext_vector_type(8))) short;
using f32x4  = __attribute__((ext_vector_type(4))) float;

__device__ __forceinline__ short f2bf(float f) {
  uint32_t u = __float_as_uint(f);
  u += 0x7fff + ((u >> 16) & 1u);
  return (short)(u >> 16);
}

#define MFMA16(a, b, c) __builtin_amdgcn_mfma_f32_16x16x32_bf16((a), (b), (c), 0, 0, 0)

// async global->LDS, 16B per lane; LDS dest is wave-uniform base + lane*16
__device__ __forceinline__ void gl_lds16(const short* g, short* l) {
  __builtin_amdgcn_global_load_lds(
      (const __attribute__((address_space(1))) void*)g,
      (__attribute__((address_space(3))) void*)l, 16, 0, 0);
}

// ---------------------------------------------------------------------------
// prep_w: pack Wq*scale|Wk|Wv -> bf16 [1152][384], Wp -> bf16, biases fp32
// ---------------------------------------------------------------------------
__global__ void prep_w(const float* __restrict__ Wq, const float* __restrict__ bq,
                       const float* __restrict__ Wk, const float* __restrict__ bk,
                       const float* __restrict__ Wv, const float* __restrict__ bv,
                       const float* __restrict__ Wp, const float* __restrict__ bp,
                       short* __restrict__ Wqkv, short* __restrict__ Wpb,
                       float* __restrict__ bqkv, float* __restrict__ bpb) {
  int i = blockIdx.x * 256 + threadIdx.x;
  const float scale = 0.17677669529663687f;  // 32^-0.5, folded into q
  if (i < 1152 * 384) {
    int r = i / 384, k = i - r * 384;
    float v;
    if (r < 384)      v = Wq[r * 384 + k] * scale;
    else if (r < 768) v = Wk[(r - 384) * 384 + k];
    else              v = Wv[(r - 768) * 384 + k];
    Wqkv[i] = f2bf(v);
  }
  if (i < 384 * 384) Wpb[i] = f2bf(Wp[i]);
  if (i < 1152) bqkv[i] = (i < 384) ? bq[i] * scale : ((i < 768) ? bk[i - 384] : bv[i - 768]);
  if (i < 384) bpb[i] = bp[i];
}

// ---------------------------------------------------------------------------
// prep_bm: bm[wm][h][i][j] = table[relidx(i,j)][h] + mask[wm][i][j]  (fp32)
// ---------------------------------------------------------------------------
__global__ void prep_bm(const float* __restrict__ table, const float* __restrict__ mask,
                        float* __restrict__ bm, int nwmask) {
  int wm = blockIdx.x / 12, h = blockIdx.x - wm * 12;
  const float* mrow = mask + (size_t)wm * 2401;
  float* dst = bm + (size_t)blockIdx.x * 2401;
  for (int e = threadIdx.x; e < 2401; e += 256) {
    int i = e / 49, j = e - i * 49;
    int id = i / 7, ir = i - id * 7;
    int jd = j / 7, jr = j - jd * 7;
    int idx = (id - jd + 6) * 13 + (ir - jr + 6);
    dst[e] = table[idx * 12 + h] + mrow[e];
  }
}

// ---------------------------------------------------------------------------
// prep_x: fp32 -> bf16 conversion of a chunk of x (8 elements / thread)
// ---------------------------------------------------------------------------
__global__ void prep_x(const float* __restrict__ x, short* __restrict__ xb, int n8) {
  int u = blockIdx.x * 256 + threadIdx.x;
  if (u < n8) {
    int e = u * 8;
    float4 f0 = *(const float4*)(x + e);
    float4 f1 = *(const float4*)(x + e + 4);
    bf16x8 cv;
    cv[0] = f2bf(f0.x); cv[1] = f2bf(f0.y); cv[2] = f2bf(f0.z); cv[3] = f2bf(f0.w);
    cv[4] = f2bf(f1.x); cv[5] = f2bf(f1.y); cv[6] = f2bf(f1.z); cv[7] = f2bf(f1.w);
    *(bf16x8*)(xb + e) = cv;
  }
}

// ---------------------------------------------------------------------------
// K1: qkv = xb @ Wqkv.T + bqkv
// q,k written [bw][h][n][32]; V written TRANSPOSED [bw][h][d][n(pad 64)] so
// attn's PV B-fragment is a single b128 load per (kk,dt).
// tile 128(M) x 192(N), 4 waves, BK=64, 2-phase dbuf pipeline.
// ---------------------------------------------------------------------------
__global__ __launch_bounds__(256) void qkv_gemm(
    const short* __restrict__ xb, const short* __restrict__ Wqkv,
    const float* __restrict__ bqkv,
    short* __restrict__ qws, short* __restrict__ kws, short* __restrict__ vws,
    int ntok) {
  // two buffers: each buf = As[128][64] | Bs[192][64] = 320*64 shorts
  __shared__ __align__(16) short smem[2 * 320 * 64];   // 80 KiB -> 2 blocks/CU
  const int tid = threadIdx.x;
  const int lane = tid & 63, wv = tid >> 6;
  const int c = lane & 15, g = lane >> 4;

  // ---- block swizzle: id -> (xq, yq), 8 rows x 6 cols per 48-id group ----
  const int mt = gridDim.y;
  int id = blockIdx.y * 6 + blockIdx.x;
  int mt8 = mt & ~7;
  int xq, yq;
  if (id < 6 * mt8) {
    int q = id / 48, r = id - q * 48;
    yq = q * 8 + (r & 7);
    xq = r >> 3;
  } else {
    int rem = id - 6 * mt8;
    xq = rem % 6;
    yq = mt8 + rem / 6;
  }
  const int n0 = xq * 192;
  const int row0 = yq * 128;

  f32x4 acc[8][3];
  const f32x4 zero = {0.f, 0.f, 0.f, 0.f};
#pragma unroll
  for (int m = 0; m < 8; m++)
#pragma unroll
    for (int nn = 0; nn < 3; nn++) acc[m][nn] = zero;

  // per-lane source swizzle: lane covers (row r0+(lane>>3), chunk lane&7);
  // logical chunk = (lane&7) ^ (r&7) with r&7 == lane>>3
  const int rsub = lane >> 3;
  const int chnk = ((lane & 7) ^ rsub) * 8;  // short offset within a 64-elt row
  const short* aS[4];
  const short* bS[6];
#pragma unroll
  for (int i = 0; i < 4; i++) {
    int r = (wv * 4 + i) * 8 + rsub;
    int grow = row0 + r;
    if (grow >= ntok) grow = ntok - 1;
    aS[i] = xb + (size_t)grow * 384 + chnk;
  }
#pragma unroll
  for (int j = 0; j < 6; j++) {
    int r = (wv * 6 + j) * 8 + rsub;
    bS[j] = Wqkv + (size_t)(n0 + r) * 384 + chnk;
  }

  auto stage = [&](int buf, int ks) {
    short* Asl = smem + buf * (320 * 64);
    short* Bsl = Asl + 128 * 64;
#pragma unroll
    for (int i = 0; i < 4; i++)
      gl_lds16(aS[i] + ks * 64, Asl + (wv * 4 + i) * 512);
#pragma unroll
    for (int j = 0; j < 6; j++)
      gl_lds16(bS[j] + ks * 64, Bsl + (wv * 6 + j) * 512);
  };

  stage(0, 0);
  __syncthreads();                 // tile 0 resident
  for (int ks = 0; ks < 6; ks++) {
    const int cur = ks & 1;
    if (ks < 5) stage(cur ^ 1, ks + 1);   // prefetch next tile
    const short* Asl = smem + cur * (320 * 64);
    const short* Bsl = Asl + 128 * 64;
#pragma unroll
    for (int kk = 0; kk < 2; kk++) {
      bf16x8 af[8];
#pragma unroll
      for (int m = 0; m < 8; m++) {
        int row = m * 16 + c;
        af[m] = *(const bf16x8*)&Asl[row * 64 + (((kk * 4 + g) ^ (row & 7)) * 8)];
      }
#pragma unroll
      for (int nn = 0; nn < 3; nn++) {
        int row = wv * 48 + nn * 16 + c;
        bf16x8 bfr = *(const bf16x8*)&Bsl[row * 64 + (((kk * 4 + g) ^ (row & 7)) * 8)];
#pragma unroll
        for (int m = 0; m < 8; m++) acc[m][nn] = MFMA16(af[m], bfr, acc[m][nn]);
      }
    }
    __syncthreads();
  }

  const int s = n0 / 384;
  const int hbase = (n0 - s * 384) >> 5;
  if (s < 2) {
    // q/k: epilogue in two 64-row halves through LDS (stride 200, b128-aligned),
    // scatter to [bw][h][n][32]
    short* base = (s == 0) ? qws : kws;
#pragma unroll
    for (int half = 0; half < 2; half++) {
      __syncthreads();
#pragma unroll
      for (int nn = 0; nn < 3; nn++) {
        int colRel = wv * 48 + nn * 16 + c;
        float bias = bqkv[n0 + colRel];
#pragma unroll
        for (int mm = 0; mm < 4; mm++) {
          int m = half * 4 + mm;
#pragma unroll
          for (int r = 0; r < 4; r++)
            smem[(mm * 16 + g * 4 + r) * 200 + colRel] = f2bf(acc[m][nn][r] + bias);
        }
      }
      __syncthreads();
      for (int u = tid; u < 384; u += 256) {
        int row = u & 63, j = u >> 6;
        int tr = row0 + half * 64 + row;
        if (tr < ntok) {
          int bw = tr / 49;
          int n = tr - bw * 49;
          short* dst = base + ((size_t)(bw * 12 + hbase + j) * 49 + n) * 32;
          const uint4* src = (const uint4*)&smem[row * 200 + j * 32];
          uint4* d4 = (uint4*)dst;
          d4[0] = src[0]; d4[1] = src[1]; d4[2] = src[2]; d4[3] = src[3];
        }
      }
    }
  } else {
    // V: transposed epilogue. smem stride 194 (odd dword stride 97 ->
    // conflict-free column reads). dst vT[(bw*12+hbase)*32 + col][n].
#pragma unroll
    for (int half = 0; half < 2; half++) {
      __syncthreads();
#pragma unroll
      for (int nn = 0; nn < 3; nn++) {
        int colRel = wv * 48 + nn * 16 + c;
        float bias = bqkv[n0 + colRel];
#pragma unroll
        for (int mm = 0; mm < 4; mm++) {
          int m = half * 4 + mm;
#pragma unroll
          for (int r = 0; r < 4; r++)
            smem[(mm * 16 + g * 4 + r) * 194 + colRel] = f2bf(acc[m][nn][r] + bias);
        }
      }
      __syncthreads();
      int row = tid & 63;
      int tr = row0 + half * 64 + row;
      if (tr < ntok) {
        int bw = tr / 49;
        int n = tr - bw * 49;
        short* wbase = vws + ((size_t)(bw * 12 + hbase) * 32) * 64 + n;
        const short* srow = &smem[row * 194];
#pragma unroll 4
        for (int it = 0; it < 48; it++) {
          int col = (tid >> 6) * 48 + it;
          wbase[(size_t)col * 64] = srow[col];
        }
      }
    }
  }
}

// ---------------------------------------------------------------------------
// K2: attention. One wave per (b,h). V-fragments prefetched upfront from
// transposed vT[b,h][d][n64] (4 x b128, issued before QK^T -> latency hidden
// under MFMA+softmax). Pad cols k in [49,64) masked to 0 in-register.
// ---------------------------------------------------------------------------
__global__ __launch_bounds__(256) void attn_kernel(
    const short* __restrict__ qws, const short* __restrict__ kws,
    const short* __restrict__ vws, short* __restrict__ ows,
    const float* __restrict__ bm, int b0, int nwmask) {
  __shared__ short Pall[4 * 64 * 72];
  const int tid = threadIdx.x;
  const int lane = tid & 63, wvi = tid >> 6;
  const int c = lane & 15, g = lane >> 4;
  const int task = blockIdx.x * 4 + wvi;   // grid = 3*nw blocks -> 12*nw tasks
  const int b = task / 12, h = task - b * 12;
  const int wm = (b0 + b) % nwmask;
  const short* qb = qws + (size_t)(b * 12 + h) * 1568;
  const short* kb = kws + (size_t)(b * 12 + h) * 1568;
  const short* vtb = vws + (size_t)(b * 12 + h) * 2048;   // [d][n64]

  bf16x8 qf[4], kf[4];
#pragma unroll
  for (int m = 0; m < 4; m++) { int i = m * 16 + c; if (i > 48) i = 48; qf[m] = *(const bf16x8*)(qb + i * 32 + g * 8); }
#pragma unroll
  for (int n = 0; n < 4; n++) { int j = n * 16 + c; if (j > 48) j = 48; kf[n] = *(const bf16x8*)(kb + j * 32 + g * 8); }

  // prefetch V fragments (independent of everything downstream)
  bf16x8 vfr[2][2];
#pragma unroll
  for (int kk = 0; kk < 2; kk++)
#pragma unroll
    for (int dt = 0; dt < 2; dt++)
      vfr[kk][dt] = *(const bf16x8*)(vtb + (dt * 16 + c) * 64 + kk * 32 + g * 8);
  // mask pad cols: k = 32 + g*8 + rr > 48  <=>  g*8+rr > 16 (kk==1 only)
#pragma unroll
  for (int dt = 0; dt < 2; dt++)
#pragma unroll
    for (int rr = 0; rr < 8; rr++)
      if (g * 8 + rr > 16) vfr[1][dt][rr] = 0;

  const f32x4 zero = {0.f, 0.f, 0.f, 0.f};
  f32x4 S[4][4];
#pragma unroll
  for (int m = 0; m < 4; m++)
#pragma unroll
    for (int n = 0; n < 4; n++) S[m][n] = MFMA16(qf[m], kf[n], zero);

  // + (rel-pos bias + mask), precomputed; invalid cols -> -3e38 (exp -> 0)
  const float* bmh = bm + (size_t)(wm * 12 + h) * 2401;
#pragma unroll
  for (int n = 0; n < 4; n++) {
    int j = n * 16 + c;
    if (j < 49) {
#pragma unroll
      for (int m = 0; m < 4; m++)
#pragma unroll
        for (int r = 0; r < 4; r++) {
          int i = m * 16 + g * 4 + r; if (i > 48) i = 48;
          S[m][n][r] += bmh[i * 49 + j];
        }
    } else {
#pragma unroll
      for (int m = 0; m < 4; m++)
#pragma unroll
        for (int r = 0; r < 4; r++) S[m][n][r] = -3.0e38f;
    }
  }

  // softmax per row (row's 64 cols live in the 16 lanes of group g)
  short* P = Pall + wvi * 4608;
#pragma unroll
  for (int m = 0; m < 4; m++)
#pragma unroll
    for (int r = 0; r < 4; r++) {
      float mx = fmaxf(fmaxf(S[m][0][r], S[m][1][r]), fmaxf(S[m][2][r], S[m][3][r]));
      mx = fmaxf(mx, __shfl_xor(mx, 1));
      mx = fmaxf(mx, __shfl_xor(mx, 2));
      mx = fmaxf(mx, __shfl_xor(mx, 4));
      mx = fmaxf(mx, __shfl_xor(mx, 8));
      float e0 = __expf(S[m][0][r] - mx);
      float e1 = __expf(S[m][1][r] - mx);
      float e2 = __expf(S[m][2][r] - mx);
      float e3 = __expf(S[m][3][r] - mx);
      float sm = (e0 + e1) + (e2 + e3);
      sm += __shfl_xor(sm, 1);
      sm += __shfl_xor(sm, 2);
      sm += __shfl_xor(sm, 4);
      sm += __shfl_xor(sm, 8);
      float rinv = 1.0f / sm;
      int row = m * 16 + g * 4 + r;
      P[row * 72 + c]      = f2bf(e0 * rinv);
      P[row * 72 + 16 + c] = f2bf(e1 * rinv);
      P[row * 72 + 32 + c] = f2bf(e2 * rinv);
      P[row * 72 + 48 + c] = f2bf(e3 * rinv);
    }
  // P is wave-private: same-wave LDS RAW ordered by lgkmcnt waits.

  f32x4 O[4][2];
#pragma unroll
  for (int m = 0; m < 4; m++) { O[m][0] = zero; O[m][1] = zero; }
#pragma unroll
  for (int kk = 0; kk < 2; kk++) {
    bf16x8 pf[4];
#pragma unroll
    for (int m = 0; m < 4; m++) pf[m] = *(const bf16x8*)&P[(m * 16 + c) * 72 + kk * 32 + g * 8];
#pragma unroll
    for (int dt = 0; dt < 2; dt++)
#pragma unroll
      for (int m = 0; m < 4; m++) O[m][dt] = MFMA16(pf[m], vfr[kk][dt], O[m][dt]);
  }
#pragma unroll
  for (int m = 0; m < 4; m++)
#pragma unroll
    for (int r = 0; r < 4; r++) {
      int i = m * 16 + g * 4 + r;
      if (i < 49) {
        size_t o = ((size_t)b * 49 + i) * 384 + h * 32;
        ows[o + c]      = f2bf(O[m][0][r]);
        ows[o + 16 + c] = f2bf(O[m][1][r]);
      }
    }
}

// ---------------------------------------------------------------------------
// K3: out = O @ Wp.T + bp ; tile 128x192 (x-blocks=2), 2-phase dbuf pipeline;
// direct fp32 coalesced stores
// ---------------------------------------------------------------------------
__global__ __launch_bounds__(256) void proj_gemm(
    const short* __restrict__ ows, const short* __restrict__ Wpb,
    const float* __restrict__ bpb, float* __restrict__ out,
    long tok0, int ntok) {
  __shared__ __align__(16) short smem[2 * 320 * 64];
  const int tid = threadIdx.x;
  const int lane = tid & 63, wv = tid >> 6;
  const int c = lane & 15, g = lane >> 4;

  // block swizzle: 8 rows x 2 cols per 16-id group
  const int mt = gridDim.y;
  int id = blockIdx.y * 2 + blockIdx.x;
  int mt8 = mt & ~7;
  int xq, yq;
  if (id < 2 * mt8) {
    int q = id / 16, r = id - q * 16;
    yq = q * 8 + (r & 7);
    xq = r >> 3;
  } else {
    int rem = id - 2 * mt8;
    xq = rem % 2;
    yq = mt8 + rem / 2;
  }
  const int n0 = xq * 192;
  const int row0 = yq * 128;

  f32x4 acc[8][3];
  const f32x4 zero = {0.f, 0.f, 0.f, 0.f};
#pragma unroll
  for (int m = 0; m < 8; m++)
#pragma unroll
    for (int nn = 0; nn < 3; nn++) acc[m][nn] = zero;

  const int rsub = lane >> 3;
  const int chnk = ((lane & 7) ^ rsub) * 8;
  const short* aS[4];
  const short* bS[6];
#pragma unroll
  for (int i = 0; i < 4; i++) {
    int r = (wv * 4 + i) * 8 + rsub;
    int grow = row0 + r;
    if (grow >= ntok) grow = ntok - 1;
    aS[i] = ows + (size_t)grow * 384 + chnk;
  }
#pragma unroll
  for (int j = 0; j < 6; j++) {
    int r = (wv * 6 + j) * 8 + rsub;
    bS[j] = Wpb + (size_t)(n0 + r) * 384 + chnk;
  }

  auto stage = [&](int buf, int ks) {
    short* Asl = smem + buf * (320 * 64);
    short* Bsl = Asl + 128 * 64;
#pragma unroll
    for (int i = 0; i < 4; i++)
      gl_lds16(aS[i] + ks * 64, Asl + (wv * 4 + i) * 512);
#pragma unroll
    for (int j = 0; j < 6; j++)
      gl_lds16(bS[j] + ks * 64, Bsl + (wv * 6 + j) * 512);
  };

  stage(0, 0);
  __syncthreads();
  for (int ks = 0; ks < 6; ks++) {
    const int cur = ks & 1;
    if (ks < 5) stage(cur ^ 1, ks + 1);
    const short* Asl = smem + cur * (320 * 64);
    const short* Bsl = Asl + 128 * 64;
#pragma unroll
    for (int kk = 0; kk < 2; kk++) {
      bf16x8 af[8];
#pragma unroll
      for (int m = 0; m < 8; m++) {
        int row = m * 16 + c;
        af[m] = *(const bf16x8*)&Asl[row * 64 + (((kk * 4 + g) ^ (row & 7)) * 8)];
      }
#pragma unroll
      for (int nn = 0; nn < 3; nn++) {
        int row = wv * 48 + nn * 16 + c;
        bf16x8 bfr = *(const bf16x8*)&Bsl[row * 64 + (((kk * 4 + g) ^ (row & 7)) * 8)];
#pragma unroll
        for (int m = 0; m < 8; m++) acc[m][nn] = MFMA16(af[m], bfr, acc[m][nn]);
      }
    }
    __syncthreads();
  }
#pragma unroll
  for (int nn = 0; nn < 3; nn++) {
    int cg = n0 + wv * 48 + nn * 16 + c;
    float bias = bpb[cg];
#pragma unroll
    for (int m = 0; m < 8; m++)
#pragma unroll
      for (int r = 0; r < 4; r++) {
        int tr = row0 + m * 16 + g * 4 + r;
        if (tr < ntok) out[((size_t)(tok0 + tr)) * 384 + cg] = acc[m][nn][r] + bias;
      }
  }
}

// ---------------------------------------------------------------------------
extern "C" void kernel_launch(void* const* d_in, const int* in_sizes, int n_in,
                              void* d_out, int out_size, void* d_ws, size_t ws_size,
                              hipStream_t stream) {
  const float* x    = (const float*)d_in[0];
  const float* mask = (const float*)d_in[1];
  const float* Wq = (const float*)d_in[2];
  const float* bq = (const float*)d_in[3];
  const float* Wk = (const float*)d_in[4];
  const float* bk = (const float*)d_in[5];
  const float* Wv = (const float*)d_in[6];
  const float* bv = (const float*)d_in[7];
  const float* Wp = (const float*)d_in[8];
  const float* bp = (const float*)d_in[9];
  const float* table = (const float*)d_in[10];
  float* out = (float*)d_out;

  const int Btot = in_sizes[0] / (49 * 384);   // 2048
  const int NWm  = in_sizes[1] / (49 * 49);    // 64

  char* ws = (char*)d_ws;
  short* Wqkv = (short*)ws;                     // 1152*384 bf16
  short* Wpb  = Wqkv + 1152 * 384;              // 384*384 bf16
  float* bqkv = (float*)(Wpb + 384 * 384);      // 1152 f32
  float* bpb  = bqkv + 1152;                    // 384 f32
  float* bmp  = bpb + 384;                      // NWm*12*2401 f32
  size_t fixedB = (size_t)(1152 * 384 + 384 * 384) * 2 + (1152 + 384) * 4
                + (size_t)NWm * 12 * 2401 * 4;
  char* dyn = ws + ((fixedB + 255) & ~(size_t)255);
  size_t used = (size_t)(dyn - ws);
  size_t avail = (ws_size > used + 4096) ? (ws_size - used - 4096) : 0;
  // per-window shorts: xb 18816 + q 18816 + k 18816 + vT 24576 + O 18816
  const size_t perw = (size_t)(4 * 18816 + 24576) * 2;
  long nwc = (long)(avail / perw);
  if (nwc > Btot) nwc = Btot;
  if (nwc >= 64) nwc &= ~63L;
  if (nwc < 1) nwc = 1;
  short* xbw = (short*)dyn;
  short* qws = xbw + (size_t)nwc * 18816;
  short* kws = qws + (size_t)nwc * 18816;
  short* vws = kws + (size_t)nwc * 18816;       // transposed: 12*32*64 per window
  short* ows = vws + (size_t)nwc * 24576;

  prep_w<<<dim3(1728), dim3(256), 0, stream>>>(Wq, bq, Wk, bk, Wv, bv, Wp, bp,
                                               Wqkv, Wpb, bqkv, bpb);
  prep_bm<<<dim3(NWm * 12), dim3(256), 0, stream>>>(table, mask, bmp, NWm);

  for (long b0 = 0; b0 < Btot; b0 += nwc) {
    int nw = (int)((Btot - b0 < nwc) ? (Btot - b0) : nwc);
    int ntok = nw * 49;
    long tok0 = b0 * 49;
    int n8 = ntok * 48;  // ntok*384/8
    prep_x<<<dim3((n8 + 255) / 256), dim3(256), 0, stream>>>(x + tok0 * 384, xbw, n8);
    int mt = (ntok + 127) / 128;
    qkv_gemm<<<dim3(6, mt), dim3(256), 0, stream>>>(xbw, Wqkv, bqkv, qws, kws, vws, ntok);
    attn_kernel<<<dim3(3 * nw), dim3(256), 0, stream>>>(qws, kws, vws, ows, bmp,
                                                        (int)b0, NWm);
    proj_gemm<<<dim3(2, mt), dim3(256), 0, stream>>>(ows, Wpb, bpb, out, tok0, ntok);
  }
}

// Round 4
// 600.670 us; speedup vs baseline: 1.1060x; 1.1060x over previous
//
#include <hip/hip_runtime.h>
#include <stdint.h>

using bf16x8 = __attribute__((ext_vector_type(8))) short;
using f32x4  = __attribute__((ext_vector_type(4))) float;

__device__ __forceinline__ short f2bf(float f) {
  uint32_t u = __float_as_uint(f);
  u += 0x7fff + ((u >> 16) & 1u);
  return (short)(u >> 16);
}

#define MFMA16(a, b, c) __builtin_amdgcn_mfma_f32_16x16x32_bf16((a), (b), (c), 0, 0, 0)

// async global->LDS, 16B per lane; LDS dest is wave-uniform base + lane*16
__device__ __forceinline__ void gl_lds16(const short* g, short* l) {
  __builtin_amdgcn_global_load_lds(
      (const __attribute__((address_space(1))) void*)g,
      (__attribute__((address_space(3))) void*)l, 16, 0, 0);
}

// ---------------------------------------------------------------------------
// prep_w: pack Wq*scale|Wk|Wv -> bf16 [1152][384], Wp -> bf16, biases fp32
// ---------------------------------------------------------------------------
__global__ void prep_w(const float* __restrict__ Wq, const float* __restrict__ bq,
                       const float* __restrict__ Wk, const float* __restrict__ bk,
                       const float* __restrict__ Wv, const float* __restrict__ bv,
                       const float* __restrict__ Wp, const float* __restrict__ bp,
                       short* __restrict__ Wqkv, short* __restrict__ Wpb,
                       float* __restrict__ bqkv, float* __restrict__ bpb) {
  int i = blockIdx.x * 256 + threadIdx.x;
  const float scale = 0.17677669529663687f;  // 32^-0.5, folded into q
  if (i < 1152 * 384) {
    int r = i / 384, k = i - r * 384;
    float v;
    if (r < 384)      v = Wq[r * 384 + k] * scale;
    else if (r < 768) v = Wk[(r - 384) * 384 + k];
    else              v = Wv[(r - 768) * 384 + k];
    Wqkv[i] = f2bf(v);
  }
  if (i < 384 * 384) Wpb[i] = f2bf(Wp[i]);
  if (i < 1152) bqkv[i] = (i < 384) ? bq[i] * scale : ((i < 768) ? bk[i - 384] : bv[i - 768]);
  if (i < 384) bpb[i] = bp[i];
}

// ---------------------------------------------------------------------------
// prep_bm: bias+mask in MFMA C-fragment layout.
// bmL[wm][h][mn(16)][c(16)][i(16)] = value for (row=(mn>>2)*16+i, col=(mn&3)*16+c)
// pad rows/cols (>=49) baked to -3e38 -> attn needs no branches, and the
// per-lane add is one coalesced dwordx4 per (m,n).
// ---------------------------------------------------------------------------
__global__ void prep_bm(const float* __restrict__ table, const float* __restrict__ mask,
                        float* __restrict__ bmL, int nwmask) {
  int wm = blockIdx.x / 12, h = blockIdx.x - wm * 12;
  const float* mrow = mask + (size_t)wm * 2401;
  float* dst = bmL + (size_t)blockIdx.x * 4096;
  for (int e = threadIdx.x; e < 4096; e += 256) {
    int mn = e >> 8, c = (e >> 4) & 15, i = e & 15;
    int row = (mn >> 2) * 16 + i, col = (mn & 3) * 16 + c;
    float v = -3.0e38f;
    if (row < 49 && col < 49) {
      int id = row / 7, ir = row - id * 7;
      int jd = col / 7, jr = col - jd * 7;
      int idx = (id - jd + 6) * 13 + (ir - jr + 6);
      v = table[idx * 12 + h] + mrow[row * 49 + col];
    }
    dst[e] = v;
  }
}

// ---------------------------------------------------------------------------
// prep_x: fp32 -> bf16 conversion of a chunk of x (8 elements / thread)
// ---------------------------------------------------------------------------
__global__ void prep_x(const float* __restrict__ x, short* __restrict__ xb, int n8) {
  int u = blockIdx.x * 256 + threadIdx.x;
  if (u < n8) {
    int e = u * 8;
    float4 f0 = *(const float4*)(x + e);
    float4 f1 = *(const float4*)(x + e + 4);
    bf16x8 cv;
    cv[0] = f2bf(f0.x); cv[1] = f2bf(f0.y); cv[2] = f2bf(f0.z); cv[3] = f2bf(f0.w);
    cv[4] = f2bf(f1.x); cv[5] = f2bf(f1.y); cv[6] = f2bf(f1.z); cv[7] = f2bf(f1.w);
    *(bf16x8*)(xb + e) = cv;
  }
}

// ---------------------------------------------------------------------------
// K1: qkv = xb @ Wqkv.T + bqkv ; writes q,k,v bf16 in [bw][h][n][32] layout
// tile 128(M) x 192(N), 4 waves, BK=64, 2-phase dbuf pipeline (round-2 proven:
// 150 us, 0 bank conflicts).
// ---------------------------------------------------------------------------
__global__ __launch_bounds__(256) void qkv_gemm(
    const short* __restrict__ xb, const short* __restrict__ Wqkv,
    const float* __restrict__ bqkv,
    short* __restrict__ qws, short* __restrict__ kws, short* __restrict__ vws,
    int ntok) {
  // two buffers: each buf = As[128][64] | Bs[192][64] = 320*64 shorts
  __shared__ __align__(16) short smem[2 * 320 * 64];   // 80 KiB -> 2 blocks/CU
  const int tid = threadIdx.x;
  const int lane = tid & 63, wv = tid >> 6;
  const int c = lane & 15, g = lane >> 4;

  // ---- block swizzle: id -> (xq, yq), 8 rows x 6 cols per 48-id group ----
  const int mt = gridDim.y;
  int id = blockIdx.y * 6 + blockIdx.x;
  int mt8 = mt & ~7;
  int xq, yq;
  if (id < 6 * mt8) {
    int q = id / 48, r = id - q * 48;
    yq = q * 8 + (r & 7);
    xq = r >> 3;
  } else {
    int rem = id - 6 * mt8;
    xq = rem % 6;
    yq = mt8 + rem / 6;
  }
  const int n0 = xq * 192;
  const int row0 = yq * 128;

  f32x4 acc[8][3];
  const f32x4 zero = {0.f, 0.f, 0.f, 0.f};
#pragma unroll
  for (int m = 0; m < 8; m++)
#pragma unroll
    for (int nn = 0; nn < 3; nn++) acc[m][nn] = zero;

  // per-lane source swizzle: lane covers (row r0+(lane>>3), chunk lane&7);
  // logical chunk = (lane&7) ^ (r&7) with r&7 == lane>>3
  const int rsub = lane >> 3;
  const int chnk = ((lane & 7) ^ rsub) * 8;  // short offset within a 64-elt row
  const short* aS[4];
  const short* bS[6];
#pragma unroll
  for (int i = 0; i < 4; i++) {
    int r = (wv * 4 + i) * 8 + rsub;
    int grow = row0 + r;
    if (grow >= ntok) grow = ntok - 1;
    aS[i] = xb + (size_t)grow * 384 + chnk;
  }
#pragma unroll
  for (int j = 0; j < 6; j++) {
    int r = (wv * 6 + j) * 8 + rsub;
    bS[j] = Wqkv + (size_t)(n0 + r) * 384 + chnk;
  }

  auto stage = [&](int buf, int ks) {
    short* Asl = smem + buf * (320 * 64);
    short* Bsl = Asl + 128 * 64;
#pragma unroll
    for (int i = 0; i < 4; i++)
      gl_lds16(aS[i] + ks * 64, Asl + (wv * 4 + i) * 512);
#pragma unroll
    for (int j = 0; j < 6; j++)
      gl_lds16(bS[j] + ks * 64, Bsl + (wv * 6 + j) * 512);
  };

  stage(0, 0);
  __syncthreads();                 // tile 0 resident
  for (int ks = 0; ks < 6; ks++) {
    const int cur = ks & 1;
    if (ks < 5) stage(cur ^ 1, ks + 1);   // prefetch next tile
    const short* Asl = smem + cur * (320 * 64);
    const short* Bsl = Asl + 128 * 64;
#pragma unroll
    for (int kk = 0; kk < 2; kk++) {
      bf16x8 af[8];
#pragma unroll
      for (int m = 0; m < 8; m++) {
        int row = m * 16 + c;
        af[m] = *(const bf16x8*)&Asl[row * 64 + (((kk * 4 + g) ^ (row & 7)) * 8)];
      }
#pragma unroll
      for (int nn = 0; nn < 3; nn++) {
        int row = wv * 48 + nn * 16 + c;
        bf16x8 bfr = *(const bf16x8*)&Bsl[row * 64 + (((kk * 4 + g) ^ (row & 7)) * 8)];
#pragma unroll
        for (int m = 0; m < 8; m++) acc[m][nn] = MFMA16(af[m], bfr, acc[m][nn]);
      }
    }
    __syncthreads();
  }

  // epilogue in two 64-row halves through LDS, scatter to [bw][h][n][32]
  const int s = n0 / 384;
  short* base = (s == 0) ? qws : ((s == 1) ? kws : vws);
  const int hbase = (n0 - s * 384) >> 5;
#pragma unroll
  for (int half = 0; half < 2; half++) {
    __syncthreads();
#pragma unroll
    for (int nn = 0; nn < 3; nn++) {
      int colRel = wv * 48 + nn * 16 + c;
      float bias = bqkv[n0 + colRel];
#pragma unroll
      for (int mm = 0; mm < 4; mm++) {
        int m = half * 4 + mm;
#pragma unroll
        for (int r = 0; r < 4; r++)
          smem[(mm * 16 + g * 4 + r) * 200 + colRel] = f2bf(acc[m][nn][r] + bias);
      }
    }
    __syncthreads();
    for (int u = tid; u < 384; u += 256) {
      int row = u & 63, j = u >> 6;
      int tr = row0 + half * 64 + row;
      if (tr < ntok) {
        int bw = tr / 49;
        int n = tr - bw * 49;
        short* dst = base + ((size_t)(bw * 12 + hbase + j) * 49 + n) * 32;
        const uint4* src = (const uint4*)&smem[row * 200 + j * 32];
        uint4* d4 = (uint4*)dst;
        d4[0] = src[0]; d4[1] = src[1]; d4[2] = src[2]; d4[3] = src[3];
      }
    }
  }
}

// ---------------------------------------------------------------------------
// K2: attention. One wave per (b,h).
// Order: qf/kf loads -> V prefetch (32 scalar, hidden under QK^T+softmax) ->
// QK^T -> vectorized bias add (bmL in C-layout, pad baked) -> softmax
// (unnormalized P; 1/sum deferred to O-scale) -> PV -> O store.
// ---------------------------------------------------------------------------
__global__ __launch_bounds__(256) void attn_kernel(
    const short* __restrict__ qws, const short* __restrict__ kws,
    const short* __restrict__ vws, short* __restrict__ ows,
    const float* __restrict__ bm, int b0, int nwmask) {
  __shared__ short Pall[4 * 64 * 72];
  const int tid = threadIdx.x;
  const int lane = tid & 63, wvi = tid >> 6;
  const int c = lane & 15, g = lane >> 4;
  const int task = blockIdx.x * 4 + wvi;   // grid = 3*nw blocks -> 12*nw tasks
  const int b = task / 12, h = task - b * 12;
  const int wm = (b0 + b) % nwmask;
  const short* qb = qws + (size_t)(b * 12 + h) * 1568;
  const short* kb = kws + (size_t)(b * 12 + h) * 1568;
  const short* vb = vws + (size_t)(b * 12 + h) * 1568;

  bf16x8 qf[4], kf[4];
#pragma unroll
  for (int m = 0; m < 4; m++) { int i = m * 16 + c; if (i > 48) i = 48; qf[m] = *(const bf16x8*)(qb + i * 32 + g * 8); }
#pragma unroll
  for (int n = 0; n < 4; n++) { int j = n * 16 + c; if (j > 48) j = 48; kf[n] = *(const bf16x8*)(kb + j * 32 + g * 8); }

  // V prefetch: issued after qf/kf (vmcnt ordering keeps QK^T un-stalled),
  // independent of everything until PV -> latency hidden.
  bf16x8 vfr[2][2];
#pragma unroll
  for (int kk = 0; kk < 2; kk++)
#pragma unroll
    for (int dt = 0; dt < 2; dt++) {
      bf16x8 vf;
#pragma unroll
      for (int rr = 0; rr < 8; rr++) {
        int j = kk * 32 + g * 8 + rr; if (j > 48) j = 48;   // P[j>=49]==0
        vf[rr] = vb[j * 32 + dt * 16 + c];
      }
      vfr[kk][dt] = vf;
    }

  const f32x4 zero = {0.f, 0.f, 0.f, 0.f};
  f32x4 S[4][4];
#pragma unroll
  for (int m = 0; m < 4; m++)
#pragma unroll
    for (int n = 0; n < 4; n++) S[m][n] = MFMA16(qf[m], kf[n], zero);

  // bias+mask: one coalesced f32x4 per (m,n); pad rows/cols pre-baked -3e38
  const float* bmh = bm + (size_t)(wm * 12 + h) * 4096;
#pragma unroll
  for (int m = 0; m < 4; m++)
#pragma unroll
    for (int n = 0; n < 4; n++) {
      f32x4 b4 = *(const f32x4*)(bmh + ((m * 4 + n) * 16 + c) * 16 + g * 4);
      S[m][n][0] += b4[0]; S[m][n][1] += b4[1];
      S[m][n][2] += b4[2]; S[m][n][3] += b4[3];
    }

  // softmax per row (row's 64 cols live in the 16 lanes of group g);
  // P unnormalized, 1/sum kept in rv[m][r] for the O epilogue
  float rv[4][4];
  short* P = Pall + wvi * 4608;
#pragma unroll
  for (int m = 0; m < 4; m++)
#pragma unroll
    for (int r = 0; r < 4; r++) {
      float mx = fmaxf(fmaxf(S[m][0][r], S[m][1][r]), fmaxf(S[m][2][r], S[m][3][r]));
      mx = fmaxf(mx, __shfl_xor(mx, 1));
      mx = fmaxf(mx, __shfl_xor(mx, 2));
      mx = fmaxf(mx, __shfl_xor(mx, 4));
      mx = fmaxf(mx, __shfl_xor(mx, 8));
      float e0 = __expf(S[m][0][r] - mx);
      float e1 = __expf(S[m][1][r] - mx);
      float e2 = __expf(S[m][2][r] - mx);
      float e3 = __expf(S[m][3][r] - mx);
      float sm = (e0 + e1) + (e2 + e3);
      sm += __shfl_xor(sm, 1);
      sm += __shfl_xor(sm, 2);
      sm += __shfl_xor(sm, 4);
      sm += __shfl_xor(sm, 8);
      rv[m][r] = 1.0f / sm;
      int row = m * 16 + g * 4 + r;
      P[row * 72 + c]      = f2bf(e0);
      P[row * 72 + 16 + c] = f2bf(e1);
      P[row * 72 + 32 + c] = f2bf(e2);
      P[row * 72 + 48 + c] = f2bf(e3);
    }
  // P is wave-private: same-wave LDS RAW ordered by lgkmcnt waits.

  f32x4 O[4][2];
#pragma unroll
  for (int m = 0; m < 4; m++) { O[m][0] = zero; O[m][1] = zero; }
#pragma unroll
  for (int kk = 0; kk < 2; kk++) {
    bf16x8 pf[4];
#pragma unroll
    for (int m = 0; m < 4; m++) pf[m] = *(const bf16x8*)&P[(m * 16 + c) * 72 + kk * 32 + g * 8];
#pragma unroll
    for (int dt = 0; dt < 2; dt++)
#pragma unroll
      for (int m = 0; m < 4; m++) O[m][dt] = MFMA16(pf[m], vfr[kk][dt], O[m][dt]);
  }
#pragma unroll
  for (int m = 0; m < 4; m++)
#pragma unroll
    for (int r = 0; r < 4; r++) {
      int i = m * 16 + g * 4 + r;
      if (i < 49) {
        size_t o = ((size_t)b * 49 + i) * 384 + h * 32;
        ows[o + c]      = f2bf(O[m][0][r] * rv[m][r]);
        ows[o + 16 + c] = f2bf(O[m][1][r] * rv[m][r]);
      }
    }
}

// ---------------------------------------------------------------------------
// K3: out = O @ Wp.T + bp ; tile 128x192 (x-blocks=2), 2-phase dbuf pipeline;
// direct fp32 coalesced stores
// ---------------------------------------------------------------------------
__global__ __launch_bounds__(256) void proj_gemm(
    const short* __restrict__ ows, const short* __restrict__ Wpb,
    const float* __restrict__ bpb, float* __restrict__ out,
    long tok0, int ntok) {
  __shared__ __align__(16) short smem[2 * 320 * 64];
  const int tid = threadIdx.x;
  const int lane = tid & 63, wv = tid >> 6;
  const int c = lane & 15, g = lane >> 4;

  // block swizzle: 8 rows x 2 cols per 16-id group
  const int mt = gridDim.y;
  int id = blockIdx.y * 2 + blockIdx.x;
  int mt8 = mt & ~7;
  int xq, yq;
  if (id < 2 * mt8) {
    int q = id / 16, r = id - q * 16;
    yq = q * 8 + (r & 7);
    xq = r >> 3;
  } else {
    int rem = id - 2 * mt8;
    xq = rem % 2;
    yq = mt8 + rem / 2;
  }
  const int n0 = xq * 192;
  const int row0 = yq * 128;

  f32x4 acc[8][3];
  const f32x4 zero = {0.f, 0.f, 0.f, 0.f};
#pragma unroll
  for (int m = 0; m < 8; m++)
#pragma unroll
    for (int nn = 0; nn < 3; nn++) acc[m][nn] = zero;

  const int rsub = lane >> 3;
  const int chnk = ((lane & 7) ^ rsub) * 8;
  const short* aS[4];
  const short* bS[6];
#pragma unroll
  for (int i = 0; i < 4; i++) {
    int r = (wv * 4 + i) * 8 + rsub;
    int grow = row0 + r;
    if (grow >= ntok) grow = ntok - 1;
    aS[i] = ows + (size_t)grow * 384 + chnk;
  }
#pragma unroll
  for (int j = 0; j < 6; j++) {
    int r = (wv * 6 + j) * 8 + rsub;
    bS[j] = Wpb + (size_t)(n0 + r) * 384 + chnk;
  }

  auto stage = [&](int buf, int ks) {
    short* Asl = smem + buf * (320 * 64);
    short* Bsl = Asl + 128 * 64;
#pragma unroll
    for (int i = 0; i < 4; i++)
      gl_lds16(aS[i] + ks * 64, Asl + (wv * 4 + i) * 512);
#pragma unroll
    for (int j = 0; j < 6; j++)
      gl_lds16(bS[j] + ks * 64, Bsl + (wv * 6 + j) * 512);
  };

  stage(0, 0);
  __syncthreads();
  for (int ks = 0; ks < 6; ks++) {
    const int cur = ks & 1;
    if (ks < 5) stage(cur ^ 1, ks + 1);
    const short* Asl = smem + cur * (320 * 64);
    const short* Bsl = Asl + 128 * 64;
#pragma unroll
    for (int kk = 0; kk < 2; kk++) {
      bf16x8 af[8];
#pragma unroll
      for (int m = 0; m < 8; m++) {
        int row = m * 16 + c;
        af[m] = *(const bf16x8*)&Asl[row * 64 + (((kk * 4 + g) ^ (row & 7)) * 8)];
      }
#pragma unroll
      for (int nn = 0; nn < 3; nn++) {
        int row = wv * 48 + nn * 16 + c;
        bf16x8 bfr = *(const bf16x8*)&Bsl[row * 64 + (((kk * 4 + g) ^ (row & 7)) * 8)];
#pragma unroll
        for (int m = 0; m < 8; m++) acc[m][nn] = MFMA16(af[m], bfr, acc[m][nn]);
      }
    }
    __syncthreads();
  }
#pragma unroll
  for (int nn = 0; nn < 3; nn++) {
    int cg = n0 + wv * 48 + nn * 16 + c;
    float bias = bpb[cg];
#pragma unroll
    for (int m = 0; m < 8; m++)
#pragma unroll
      for (int r = 0; r < 4; r++) {
        int tr = row0 + m * 16 + g * 4 + r;
        if (tr < ntok) out[((size_t)(tok0 + tr)) * 384 + cg] = acc[m][nn][r] + bias;
      }
  }
}

// ---------------------------------------------------------------------------
extern "C" void kernel_launch(void* const* d_in, const int* in_sizes, int n_in,
                              void* d_out, int out_size, void* d_ws, size_t ws_size,
                              hipStream_t stream) {
  const float* x    = (const float*)d_in[0];
  const float* mask = (const float*)d_in[1];
  const float* Wq = (const float*)d_in[2];
  const float* bq = (const float*)d_in[3];
  const float* Wk = (const float*)d_in[4];
  const float* bk = (const float*)d_in[5];
  const float* Wv = (const float*)d_in[6];
  const float* bv = (const float*)d_in[7];
  const float* Wp = (const float*)d_in[8];
  const float* bp = (const float*)d_in[9];
  const float* table = (const float*)d_in[10];
  float* out = (float*)d_out;

  const int Btot = in_sizes[0] / (49 * 384);   // 2048
  const int NWm  = in_sizes[1] / (49 * 49);    // 64

  char* ws = (char*)d_ws;
  short* Wqkv = (short*)ws;                     // 1152*384 bf16
  short* Wpb  = Wqkv + 1152 * 384;              // 384*384 bf16
  float* bqkv = (float*)(Wpb + 384 * 384);      // 1152 f32
  float* bpb  = bqkv + 1152;                    // 384 f32
  float* bmp  = bpb + 384;                      // NWm*12*4096 f32 (C-layout)
  size_t fixedB = (size_t)(1152 * 384 + 384 * 384) * 2 + (1152 + 384) * 4
                + (size_t)NWm * 12 * 4096 * 4;
  char* dyn = ws + ((fixedB + 255) & ~(size_t)255);
  size_t used = (size_t)(dyn - ws);
  size_t avail = (ws_size > used + 4096) ? (ws_size - used - 4096) : 0;
  const size_t perw = (size_t)5 * 18816 * 2;    // xb,q,k,v,O bf16 per window
  long nwc = (long)(avail / perw);
  if (nwc > Btot) nwc = Btot;
  if (nwc >= 64) nwc &= ~63L;
  if (nwc < 1) nwc = 1;
  short* xbw = (short*)dyn;
  short* qws = xbw + (size_t)nwc * 18816;
  short* kws = qws + (size_t)nwc * 18816;
  short* vws = kws + (size_t)nwc * 18816;
  short* ows = vws + (size_t)nwc * 18816;

  prep_w<<<dim3(1728), dim3(256), 0, stream>>>(Wq, bq, Wk, bk, Wv, bv, Wp, bp,
                                               Wqkv, Wpb, bqkv, bpb);
  prep_bm<<<dim3(NWm * 12), dim3(256), 0, stream>>>(table, mask, bmp, NWm);

  for (long b0 = 0; b0 < Btot; b0 += nwc) {
    int nw = (int)((Btot - b0 < nwc) ? (Btot - b0) : nwc);
    int ntok = nw * 49;
    long tok0 = b0 * 49;
    int n8 = ntok * 48;  // ntok*384/8
    prep_x<<<dim3((n8 + 255) / 256), dim3(256), 0, stream>>>(x + tok0 * 384, xbw, n8);
    int mt = (ntok + 127) / 128;
    qkv_gemm<<<dim3(6, mt), dim3(256), 0, stream>>>(xbw, Wqkv, bqkv, qws, kws, vws, ntok);
    attn_kernel<<<dim3(3 * nw), dim3(256), 0, stream>>>(qws, kws, vws, ows, bmp,
                                                        (int)b0, NWm);
    proj_gemm<<<dim3(2, mt), dim3(256), 0, stream>>>(ows, Wpb, bpb, out, tok0, ntok);
  }
}

// Round 5
// 589.525 us; speedup vs baseline: 1.1269x; 1.0189x over previous
//
#include <hip/hip_runtime.h>
#include <stdint.h>

using bf16x8 = __attribute__((ext_vector_type(8))) short;
using f32x4  = __attribute__((ext_vector_type(4))) float;

__device__ __forceinline__ short f2bf(float f) {
  uint32_t u = __float_as_uint(f);
  u += 0x7fff + ((u >> 16) & 1u);
  return (short)(u >> 16);
}

#define MFMA16(a, b, c) __builtin_amdgcn_mfma_f32_16x16x32_bf16((a), (b), (c), 0, 0, 0)

// async global->LDS, 16B per lane; LDS dest is wave-uniform base + lane*16
__device__ __forceinline__ void gl_lds16(const short* g, short* l) {
  __builtin_amdgcn_global_load_lds(
      (const __attribute__((address_space(1))) void*)g,
      (__attribute__((address_space(3))) void*)l, 16, 0, 0);
}

// ---------------------------------------------------------------------------
// prep_w: pack Wq*scale|Wk|Wv -> bf16 [1152][384], Wp -> bf16, biases fp32
// ---------------------------------------------------------------------------
__global__ void prep_w(const float* __restrict__ Wq, const float* __restrict__ bq,
                       const float* __restrict__ Wk, const float* __restrict__ bk,
                       const float* __restrict__ Wv, const float* __restrict__ bv,
                       const float* __restrict__ Wp, const float* __restrict__ bp,
                       short* __restrict__ Wqkv, short* __restrict__ Wpb,
                       float* __restrict__ bqkv, float* __restrict__ bpb) {
  int i = blockIdx.x * 256 + threadIdx.x;
  const float scale = 0.17677669529663687f;  // 32^-0.5, folded into q
  if (i < 1152 * 384) {
    int r = i / 384, k = i - r * 384;
    float v;
    if (r < 384)      v = Wq[r * 384 + k] * scale;
    else if (r < 768) v = Wk[(r - 384) * 384 + k];
    else              v = Wv[(r - 768) * 384 + k];
    Wqkv[i] = f2bf(v);
  }
  if (i < 384 * 384) Wpb[i] = f2bf(Wp[i]);
  if (i < 1152) bqkv[i] = (i < 384) ? bq[i] * scale : ((i < 768) ? bk[i - 384] : bv[i - 768]);
  if (i < 384) bpb[i] = bp[i];
}

// ---------------------------------------------------------------------------
// prep_bm: bias+mask in MFMA C-fragment layout.
// bmL[wm][h][mn(16)][c(16)][i(16)] = value for (row=(mn>>2)*16+i, col=(mn&3)*16+c)
// pad rows/cols (>=49) baked to -3e38.
// ---------------------------------------------------------------------------
__global__ void prep_bm(const float* __restrict__ table, const float* __restrict__ mask,
                        float* __restrict__ bmL, int nwmask) {
  int wm = blockIdx.x / 12, h = blockIdx.x - wm * 12;
  const float* mrow = mask + (size_t)wm * 2401;
  float* dst = bmL + (size_t)blockIdx.x * 4096;
  for (int e = threadIdx.x; e < 4096; e += 256) {
    int mn = e >> 8, c = (e >> 4) & 15, i = e & 15;
    int row = (mn >> 2) * 16 + i, col = (mn & 3) * 16 + c;
    float v = -3.0e38f;
    if (row < 49 && col < 49) {
      int id = row / 7, ir = row - id * 7;
      int jd = col / 7, jr = col - jd * 7;
      int idx = (id - jd + 6) * 13 + (ir - jr + 6);
      v = table[idx * 12 + h] + mrow[row * 49 + col];
    }
    dst[e] = v;
  }
}

// ---------------------------------------------------------------------------
// prep_x: fp32 -> bf16 conversion of a chunk of x (8 elements / thread)
// ---------------------------------------------------------------------------
__global__ void prep_x(const float* __restrict__ x, short* __restrict__ xb, int n8) {
  int u = blockIdx.x * 256 + threadIdx.x;
  if (u < n8) {
    int e = u * 8;
    float4 f0 = *(const float4*)(x + e);
    float4 f1 = *(const float4*)(x + e + 4);
    bf16x8 cv;
    cv[0] = f2bf(f0.x); cv[1] = f2bf(f0.y); cv[2] = f2bf(f0.z); cv[3] = f2bf(f0.w);
    cv[4] = f2bf(f1.x); cv[5] = f2bf(f1.y); cv[6] = f2bf(f1.z); cv[7] = f2bf(f1.w);
    *(bf16x8*)(xb + e) = cv;
  }
}

// ---------------------------------------------------------------------------
// K1: qkv = xb @ Wqkv.T + bqkv ; writes q,k,v bf16 in [bw][h][n][32] layout
// tile 128(M) x 192(N), 4 waves, BK=64, 2-phase dbuf with COUNTED vmcnt:
// raw s_barrier + s_waitcnt vmcnt(10) keeps the next tile's 10 loads in
// flight across the barrier (T4, m218/m139 pattern); only the prologue and
// last iter drain to vmcnt(0).
// ---------------------------------------------------------------------------
__global__ __launch_bounds__(256) void qkv_gemm(
    const short* __restrict__ xb, const short* __restrict__ Wqkv,
    const float* __restrict__ bqkv,
    short* __restrict__ qws, short* __restrict__ kws, short* __restrict__ vws,
    int ntok) {
  // two buffers: each buf = As[128][64] | Bs[192][64] = 320*64 shorts
  __shared__ __align__(16) short smem[2 * 320 * 64];   // 80 KiB -> 2 blocks/CU
  const int tid = threadIdx.x;
  const int lane = tid & 63, wv = tid >> 6;
  const int c = lane & 15, g = lane >> 4;

  // ---- block swizzle: id -> (xq, yq), 8 rows x 6 cols per 48-id group ----
  const int mt = gridDim.y;
  int id = blockIdx.y * 6 + blockIdx.x;
  int mt8 = mt & ~7;
  int xq, yq;
  if (id < 6 * mt8) {
    int q = id / 48, r = id - q * 48;
    yq = q * 8 + (r & 7);
    xq = r >> 3;
  } else {
    int rem = id - 6 * mt8;
    xq = rem % 6;
    yq = mt8 + rem / 6;
  }
  const int n0 = xq * 192;
  const int row0 = yq * 128;

  f32x4 acc[8][3];
  const f32x4 zero = {0.f, 0.f, 0.f, 0.f};
#pragma unroll
  for (int m = 0; m < 8; m++)
#pragma unroll
    for (int nn = 0; nn < 3; nn++) acc[m][nn] = zero;

  // per-lane source swizzle: lane covers (row r0+(lane>>3), chunk lane&7);
  // logical chunk = (lane&7) ^ (r&7) with r&7 == lane>>3
  const int rsub = lane >> 3;
  const int chnk = ((lane & 7) ^ rsub) * 8;  // short offset within a 64-elt row
  const short* aS[4];
  const short* bS[6];
#pragma unroll
  for (int i = 0; i < 4; i++) {
    int r = (wv * 4 + i) * 8 + rsub;
    int grow = row0 + r;
    if (grow >= ntok) grow = ntok - 1;
    aS[i] = xb + (size_t)grow * 384 + chnk;
  }
#pragma unroll
  for (int j = 0; j < 6; j++) {
    int r = (wv * 6 + j) * 8 + rsub;
    bS[j] = Wqkv + (size_t)(n0 + r) * 384 + chnk;
  }

  auto stage = [&](int buf, int ks) {
    short* Asl = smem + buf * (320 * 64);
    short* Bsl = Asl + 128 * 64;
#pragma unroll
    for (int i = 0; i < 4; i++)
      gl_lds16(aS[i] + ks * 64, Asl + (wv * 4 + i) * 512);
#pragma unroll
    for (int j = 0; j < 6; j++)
      gl_lds16(bS[j] + ks * 64, Bsl + (wv * 6 + j) * 512);
  };

  stage(0, 0);
  asm volatile("s_waitcnt vmcnt(0)" ::: "memory");
  __builtin_amdgcn_s_barrier();            // tile 0 resident for all waves
#pragma unroll
  for (int ks = 0; ks < 6; ks++) {
    const int cur = ks & 1;
    if (ks < 5) {
      stage(cur ^ 1, ks + 1);              // +10 loads, stay in flight
      asm volatile("s_waitcnt vmcnt(10)" ::: "memory");  // oldest 10 (= cur) done
    } else {
      asm volatile("s_waitcnt vmcnt(0)" ::: "memory");
    }
    __builtin_amdgcn_sched_barrier(0);     // rule 18: pin waitcnt before barrier
    __builtin_amdgcn_s_barrier();          // all waves' cur loads done
    const short* Asl = smem + cur * (320 * 64);
    const short* Bsl = Asl + 128 * 64;
#pragma unroll
    for (int kk = 0; kk < 2; kk++) {
      bf16x8 af[8];
#pragma unroll
      for (int m = 0; m < 8; m++) {
        int row = m * 16 + c;
        af[m] = *(const bf16x8*)&Asl[row * 64 + (((kk * 4 + g) ^ (row & 7)) * 8)];
      }
#pragma unroll
      for (int nn = 0; nn < 3; nn++) {
        int row = wv * 48 + nn * 16 + c;
        bf16x8 bfr = *(const bf16x8*)&Bsl[row * 64 + (((kk * 4 + g) ^ (row & 7)) * 8)];
#pragma unroll
        for (int m = 0; m < 8; m++) acc[m][nn] = MFMA16(af[m], bfr, acc[m][nn]);
      }
    }
    __builtin_amdgcn_sched_barrier(0);
    __builtin_amdgcn_s_barrier();          // readers of cur done before re-stage
  }

  // epilogue in two 64-row halves through LDS, scatter to [bw][h][n][32]
  const int s = n0 / 384;
  short* base = (s == 0) ? qws : ((s == 1) ? kws : vws);
  const int hbase = (n0 - s * 384) >> 5;
#pragma unroll
  for (int half = 0; half < 2; half++) {
    __syncthreads();
#pragma unroll
    for (int nn = 0; nn < 3; nn++) {
      int colRel = wv * 48 + nn * 16 + c;
      float bias = bqkv[n0 + colRel];
#pragma unroll
      for (int mm = 0; mm < 4; mm++) {
        int m = half * 4 + mm;
#pragma unroll
        for (int r = 0; r < 4; r++)
          smem[(mm * 16 + g * 4 + r) * 200 + colRel] = f2bf(acc[m][nn][r] + bias);
      }
    }
    __syncthreads();
    for (int u = tid; u < 384; u += 256) {
      int row = u & 63, j = u >> 6;
      int tr = row0 + half * 64 + row;
      if (tr < ntok) {
        int bw = tr / 49;
        int n = tr - bw * 49;
        short* dst = base + ((size_t)(bw * 12 + hbase + j) * 49 + n) * 32;
        const uint4* src = (const uint4*)&smem[row * 200 + j * 32];
        uint4* d4 = (uint4*)dst;
        d4[0] = src[0]; d4[1] = src[1]; d4[2] = src[2]; d4[3] = src[3];
      }
    }
  }
}

// ---------------------------------------------------------------------------
// K2: attention. One wave per (b,h). qf/kf loads -> V prefetch -> QK^T
// (setprio) -> vectorized bias add -> softmax (unnormalized P; 1/sum at
// O-scale) -> PV (setprio) -> O store. setprio = T5 (m191 regime:
// independent waves at different phases).
// ---------------------------------------------------------------------------
__global__ __launch_bounds__(256) void attn_kernel(
    const short* __restrict__ qws, const short* __restrict__ kws,
    const short* __restrict__ vws, short* __restrict__ ows,
    const float* __restrict__ bm, int b0, int nwmask) {
  __shared__ short Pall[4 * 64 * 72];
  const int tid = threadIdx.x;
  const int lane = tid & 63, wvi = tid >> 6;
  const int c = lane & 15, g = lane >> 4;
  const int task = blockIdx.x * 4 + wvi;   // grid = 3*nw blocks -> 12*nw tasks
  const int b = task / 12, h = task - b * 12;
  const int wm = (b0 + b) % nwmask;
  const short* qb = qws + (size_t)(b * 12 + h) * 1568;
  const short* kb = kws + (size_t)(b * 12 + h) * 1568;
  const short* vb = vws + (size_t)(b * 12 + h) * 1568;

  bf16x8 qf[4], kf[4];
#pragma unroll
  for (int m = 0; m < 4; m++) { int i = m * 16 + c; if (i > 48) i = 48; qf[m] = *(const bf16x8*)(qb + i * 32 + g * 8); }
#pragma unroll
  for (int n = 0; n < 4; n++) { int j = n * 16 + c; if (j > 48) j = 48; kf[n] = *(const bf16x8*)(kb + j * 32 + g * 8); }

  // V prefetch: issued after qf/kf, independent until PV -> latency hidden.
  bf16x8 vfr[2][2];
#pragma unroll
  for (int kk = 0; kk < 2; kk++)
#pragma unroll
    for (int dt = 0; dt < 2; dt++) {
      bf16x8 vf;
#pragma unroll
      for (int rr = 0; rr < 8; rr++) {
        int j = kk * 32 + g * 8 + rr; if (j > 48) j = 48;   // P[j>=49]==0
        vf[rr] = vb[j * 32 + dt * 16 + c];
      }
      vfr[kk][dt] = vf;
    }

  const f32x4 zero = {0.f, 0.f, 0.f, 0.f};
  f32x4 S[4][4];
  __builtin_amdgcn_s_setprio(1);
#pragma unroll
  for (int m = 0; m < 4; m++)
#pragma unroll
    for (int n = 0; n < 4; n++) S[m][n] = MFMA16(qf[m], kf[n], zero);
  __builtin_amdgcn_s_setprio(0);

  // bias+mask: one coalesced f32x4 per (m,n); pad rows/cols pre-baked -3e38
  const float* bmh = bm + (size_t)(wm * 12 + h) * 4096;
#pragma unroll
  for (int m = 0; m < 4; m++)
#pragma unroll
    for (int n = 0; n < 4; n++) {
      f32x4 b4 = *(const f32x4*)(bmh + ((m * 4 + n) * 16 + c) * 16 + g * 4);
      S[m][n][0] += b4[0]; S[m][n][1] += b4[1];
      S[m][n][2] += b4[2]; S[m][n][3] += b4[3];
    }

  // softmax per row (row's 64 cols live in the 16 lanes of group g);
  // P unnormalized, 1/sum kept in rv[m][r] for the O epilogue
  float rv[4][4];
  short* P = Pall + wvi * 4608;
#pragma unroll
  for (int m = 0; m < 4; m++)
#pragma unroll
    for (int r = 0; r < 4; r++) {
      float mx = fmaxf(fmaxf(S[m][0][r], S[m][1][r]), fmaxf(S[m][2][r], S[m][3][r]));
      mx = fmaxf(mx, __shfl_xor(mx, 1));
      mx = fmaxf(mx, __shfl_xor(mx, 2));
      mx = fmaxf(mx, __shfl_xor(mx, 4));
      mx = fmaxf(mx, __shfl_xor(mx, 8));
      float e0 = __expf(S[m][0][r] - mx);
      float e1 = __expf(S[m][1][r] - mx);
      float e2 = __expf(S[m][2][r] - mx);
      float e3 = __expf(S[m][3][r] - mx);
      float sm = (e0 + e1) + (e2 + e3);
      sm += __shfl_xor(sm, 1);
      sm += __shfl_xor(sm, 2);
      sm += __shfl_xor(sm, 4);
      sm += __shfl_xor(sm, 8);
      rv[m][r] = 1.0f / sm;
      int row = m * 16 + g * 4 + r;
      P[row * 72 + c]      = f2bf(e0);
      P[row * 72 + 16 + c] = f2bf(e1);
      P[row * 72 + 32 + c] = f2bf(e2);
      P[row * 72 + 48 + c] = f2bf(e3);
    }
  // P is wave-private: same-wave LDS RAW ordered by lgkmcnt waits.

  f32x4 O[4][2];
#pragma unroll
  for (int m = 0; m < 4; m++) { O[m][0] = zero; O[m][1] = zero; }
#pragma unroll
  for (int kk = 0; kk < 2; kk++) {
    bf16x8 pf[4];
#pragma unroll
    for (int m = 0; m < 4; m++) pf[m] = *(const bf16x8*)&P[(m * 16 + c) * 72 + kk * 32 + g * 8];
    __builtin_amdgcn_s_setprio(1);
#pragma unroll
    for (int dt = 0; dt < 2; dt++)
#pragma unroll
      for (int m = 0; m < 4; m++) O[m][dt] = MFMA16(pf[m], vfr[kk][dt], O[m][dt]);
    __builtin_amdgcn_s_setprio(0);
  }
#pragma unroll
  for (int m = 0; m < 4; m++)
#pragma unroll
    for (int r = 0; r < 4; r++) {
      int i = m * 16 + g * 4 + r;
      if (i < 49) {
        size_t o = ((size_t)b * 49 + i) * 384 + h * 32;
        ows[o + c]      = f2bf(O[m][0][r] * rv[m][r]);
        ows[o + 16 + c] = f2bf(O[m][1][r] * rv[m][r]);
      }
    }
}

// ---------------------------------------------------------------------------
// K3: out = O @ Wp.T + bp ; tile 128x192 (x-blocks=2), counted-vmcnt 2-phase
// pipeline like K1; direct fp32 coalesced stores
// ---------------------------------------------------------------------------
__global__ __launch_bounds__(256) void proj_gemm(
    const short* __restrict__ ows, const short* __restrict__ Wpb,
    const float* __restrict__ bpb, float* __restrict__ out,
    long tok0, int ntok) {
  __shared__ __align__(16) short smem[2 * 320 * 64];
  const int tid = threadIdx.x;
  const int lane = tid & 63, wv = tid >> 6;
  const int c = lane & 15, g = lane >> 4;

  // block swizzle: 8 rows x 2 cols per 16-id group
  const int mt = gridDim.y;
  int id = blockIdx.y * 2 + blockIdx.x;
  int mt8 = mt & ~7;
  int xq, yq;
  if (id < 2 * mt8) {
    int q = id / 16, r = id - q * 16;
    yq = q * 8 + (r & 7);
    xq = r >> 3;
  } else {
    int rem = id - 2 * mt8;
    xq = rem % 2;
    yq = mt8 + rem / 2;
  }
  const int n0 = xq * 192;
  const int row0 = yq * 128;

  f32x4 acc[8][3];
  const f32x4 zero = {0.f, 0.f, 0.f, 0.f};
#pragma unroll
  for (int m = 0; m < 8; m++)
#pragma unroll
    for (int nn = 0; nn < 3; nn++) acc[m][nn] = zero;

  const int rsub = lane >> 3;
  const int chnk = ((lane & 7) ^ rsub) * 8;
  const short* aS[4];
  const short* bS[6];
#pragma unroll
  for (int i = 0; i < 4; i++) {
    int r = (wv * 4 + i) * 8 + rsub;
    int grow = row0 + r;
    if (grow >= ntok) grow = ntok - 1;
    aS[i] = ows + (size_t)grow * 384 + chnk;
  }
#pragma unroll
  for (int j = 0; j < 6; j++) {
    int r = (wv * 6 + j) * 8 + rsub;
    bS[j] = Wpb + (size_t)(n0 + r) * 384 + chnk;
  }

  auto stage = [&](int buf, int ks) {
    short* Asl = smem + buf * (320 * 64);
    short* Bsl = Asl + 128 * 64;
#pragma unroll
    for (int i = 0; i < 4; i++)
      gl_lds16(aS[i] + ks * 64, Asl + (wv * 4 + i) * 512);
#pragma unroll
    for (int j = 0; j < 6; j++)
      gl_lds16(bS[j] + ks * 64, Bsl + (wv * 6 + j) * 512);
  };

  stage(0, 0);
  asm volatile("s_waitcnt vmcnt(0)" ::: "memory");
  __builtin_amdgcn_s_barrier();
#pragma unroll
  for (int ks = 0; ks < 6; ks++) {
    const int cur = ks & 1;
    if (ks < 5) {
      stage(cur ^ 1, ks + 1);
      asm volatile("s_waitcnt vmcnt(10)" ::: "memory");
    } else {
      asm volatile("s_waitcnt vmcnt(0)" ::: "memory");
    }
    __builtin_amdgcn_sched_barrier(0);
    __builtin_amdgcn_s_barrier();
    const short* Asl = smem + cur * (320 * 64);
    const short* Bsl = Asl + 128 * 64;
#pragma unroll
    for (int kk = 0; kk < 2; kk++) {
      bf16x8 af[8];
#pragma unroll
      for (int m = 0; m < 8; m++) {
        int row = m * 16 + c;
        af[m] = *(const bf16x8*)&Asl[row * 64 + (((kk * 4 + g) ^ (row & 7)) * 8)];
      }
#pragma unroll
      for (int nn = 0; nn < 3; nn++) {
        int row = wv * 48 + nn * 16 + c;
        bf16x8 bfr = *(const bf16x8*)&Bsl[row * 64 + (((kk * 4 + g) ^ (row & 7)) * 8)];
#pragma unroll
        for (int m = 0; m < 8; m++) acc[m][nn] = MFMA16(af[m], bfr, acc[m][nn]);
      }
    }
    __builtin_amdgcn_sched_barrier(0);
    __builtin_amdgcn_s_barrier();
  }
#pragma unroll
  for (int nn = 0; nn < 3; nn++) {
    int cg = n0 + wv * 48 + nn * 16 + c;
    float bias = bpb[cg];
#pragma unroll
    for (int m = 0; m < 8; m++)
#pragma unroll
      for (int r = 0; r < 4; r++) {
        int tr = row0 + m * 16 + g * 4 + r;
        if (tr < ntok) out[((size_t)(tok0 + tr)) * 384 + cg] = acc[m][nn][r] + bias;
      }
  }
}

// ---------------------------------------------------------------------------
extern "C" void kernel_launch(void* const* d_in, const int* in_sizes, int n_in,
                              void* d_out, int out_size, void* d_ws, size_t ws_size,
                              hipStream_t stream) {
  const float* x    = (const float*)d_in[0];
  const float* mask = (const float*)d_in[1];
  const float* Wq = (const float*)d_in[2];
  const float* bq = (const float*)d_in[3];
  const float* Wk = (const float*)d_in[4];
  const float* bk = (const float*)d_in[5];
  const float* Wv = (const float*)d_in[6];
  const float* bv = (const float*)d_in[7];
  const float* Wp = (const float*)d_in[8];
  const float* bp = (const float*)d_in[9];
  const float* table = (const float*)d_in[10];
  float* out = (float*)d_out;

  const int Btot = in_sizes[0] / (49 * 384);   // 2048
  const int NWm  = in_sizes[1] / (49 * 49);    // 64

  char* ws = (char*)d_ws;
  short* Wqkv = (short*)ws;                     // 1152*384 bf16
  short* Wpb  = Wqkv + 1152 * 384;              // 384*384 bf16
  float* bqkv = (float*)(Wpb + 384 * 384);      // 1152 f32
  float* bpb  = bqkv + 1152;                    // 384 f32
  float* bmp  = bpb + 384;                      // NWm*12*4096 f32 (C-layout)
  size_t fixedB = (size_t)(1152 * 384 + 384 * 384) * 2 + (1152 + 384) * 4
                + (size_t)NWm * 12 * 4096 * 4;
  char* dyn = ws + ((fixedB + 255) & ~(size_t)255);
  size_t used = (size_t)(dyn - ws);
  size_t avail = (ws_size > used + 4096) ? (ws_size - used - 4096) : 0;
  const size_t perw = (size_t)5 * 18816 * 2;    // xb,q,k,v,O bf16 per window
  long nwc = (long)(avail / perw);
  if (nwc > Btot) nwc = Btot;
  if (nwc >= 64) nwc &= ~63L;
  if (nwc < 1) nwc = 1;
  short* xbw = (short*)dyn;
  short* qws = xbw + (size_t)nwc * 18816;
  short* kws = qws + (size_t)nwc * 18816;
  short* vws = kws + (size_t)nwc * 18816;
  short* ows = vws + (size_t)nwc * 18816;

  prep_w<<<dim3(1728), dim3(256), 0, stream>>>(Wq, bq, Wk, bk, Wv, bv, Wp, bp,
                                               Wqkv, Wpb, bqkv, bpb);
  prep_bm<<<dim3(NWm * 12), dim3(256), 0, stream>>>(table, mask, bmp, NWm);

  for (long b0 = 0; b0 < Btot; b0 += nwc) {
    int nw = (int)((Btot - b0 < nwc) ? (Btot - b0) : nwc);
    int ntok = nw * 49;
    long tok0 = b0 * 49;
    int n8 = ntok * 48;  // ntok*384/8
    prep_x<<<dim3((n8 + 255) / 256), dim3(256), 0, stream>>>(x + tok0 * 384, xbw, n8);
    int mt = (ntok + 127) / 128;
    qkv_gemm<<<dim3(6, mt), dim3(256), 0, stream>>>(xbw, Wqkv, bqkv, qws, kws, vws, ntok);
    attn_kernel<<<dim3(3 * nw), dim3(256), 0, stream>>>(qws, kws, vws, ows, bmp,
                                                        (int)b0, NWm);
    proj_gemm<<<dim3(2, mt), dim3(256), 0, stream>>>(ows, Wpb, bpb, out, tok0, ntok);
  }
}

// Round 6
// 570.469 us; speedup vs baseline: 1.1645x; 1.0334x over previous
//
#include <hip/hip_runtime.h>
#include <stdint.h>

using bf16x8 = __attribute__((ext_vector_type(8))) short;
using f32x4  = __attribute__((ext_vector_type(4))) float;

__device__ __forceinline__ short f2bf(float f) {
  uint32_t u = __float_as_uint(f);
  u += 0x7fff + ((u >> 16) & 1u);
  return (short)(u >> 16);
}

#define MFMA16(a, b, c) __builtin_amdgcn_mfma_f32_16x16x32_bf16((a), (b), (c), 0, 0, 0)

// async global->LDS, 16B per lane; LDS dest is wave-uniform base + lane*16
__device__ __forceinline__ void gl_lds16(const short* g, short* l) {
  __builtin_amdgcn_global_load_lds(
      (const __attribute__((address_space(1))) void*)g,
      (__attribute__((address_space(3))) void*)l, 16, 0, 0);
}

// ---------------------------------------------------------------------------
// prep_w: pack Wq*scale|Wk|Wv -> bf16 [1152][384], Wp -> bf16, biases fp32
// ---------------------------------------------------------------------------
__global__ void prep_w(const float* __restrict__ Wq, const float* __restrict__ bq,
                       const float* __restrict__ Wk, const float* __restrict__ bk,
                       const float* __restrict__ Wv, const float* __restrict__ bv,
                       const float* __restrict__ Wp, const float* __restrict__ bp,
                       short* __restrict__ Wqkv, short* __restrict__ Wpb,
                       float* __restrict__ bqkv, float* __restrict__ bpb) {
  int i = blockIdx.x * 256 + threadIdx.x;
  const float scale = 0.17677669529663687f;  // 32^-0.5, folded into q
  if (i < 1152 * 384) {
    int r = i / 384, k = i - r * 384;
    float v;
    if (r < 384)      v = Wq[r * 384 + k] * scale;
    else if (r < 768) v = Wk[(r - 384) * 384 + k];
    else              v = Wv[(r - 768) * 384 + k];
    Wqkv[i] = f2bf(v);
  }
  if (i < 384 * 384) Wpb[i] = f2bf(Wp[i]);
  if (i < 1152) bqkv[i] = (i < 384) ? bq[i] * scale : ((i < 768) ? bk[i - 384] : bv[i - 768]);
  if (i < 384) bpb[i] = bp[i];
}

// ---------------------------------------------------------------------------
// prep_bm: bias+mask baked in the SWAPPED-QK^T C-fragment layout.
// bmT[wm][h][mn(16)][c(16)][i(16)] = bias(row_q=(mn>>2)*16+c, col_k=(mn&3)*16+i)
// pad rows/cols (>=49) -> -3e38 (finite: avoids inf-inf NaN; exp -> 0).
// attn loads f32x4 at ((m*4+n)*16+c)*16 + g*4 -> matches St[m][n][r] at
// lane (c,g) = S[q=m*16+c][k=n*16+g*4+r].
// ---------------------------------------------------------------------------
__global__ void prep_bm(const float* __restrict__ table, const float* __restrict__ mask,
                        float* __restrict__ bmT, int nwmask) {
  int wm = blockIdx.x / 12, h = blockIdx.x - wm * 12;
  const float* mrow = mask + (size_t)wm * 2401;
  float* dst = bmT + (size_t)blockIdx.x * 4096;
  for (int e = threadIdx.x; e < 4096; e += 256) {
    int mn = e >> 8, cf = (e >> 4) & 15, if_ = e & 15;
    int row = (mn >> 2) * 16 + cf;   // q-row from c-field (swapped layout)
    int col = (mn & 3) * 16 + if_;   // k-col from i-field
    float v = -3.0e38f;
    if (row < 49 && col < 49) {
      int id = row / 7, ir = row - id * 7;
      int jd = col / 7, jr = col - jd * 7;
      int idx = (id - jd + 6) * 13 + (ir - jr + 6);
      v = table[idx * 12 + h] + mrow[row * 49 + col];
    }
    dst[e] = v;
  }
}

// ---------------------------------------------------------------------------
// K1: qkv = f32 x @ Wqkv.T + bqkv ; fp32->bf16 conversion FUSED into A-staging
// (prep_x eliminated). q,k,v bf16 out in [bw][h][n][32] layout.
// tile 128(M) x 192(N), 4 waves, BK=64, 2-phase dbuf:
//   loadA(next->regs) + gl_lds B(next)  [issued before compute: T14 hide]
//   MFMA(cur)
//   cvt+ds_write A(next)                [vmcnt wait on own loads only]
//   one __syncthreads per iter          [drains B gl_lds + A ds_writes]
// A LDS layout identical to before (XOR-swizzled chunks), written by ds_write.
// ---------------------------------------------------------------------------
__global__ __launch_bounds__(256) void qkv_gemm(
    const float* __restrict__ xf, const short* __restrict__ Wqkv,
    const float* __restrict__ bqkv,
    short* __restrict__ qws, short* __restrict__ kws, short* __restrict__ vws,
    int ntok) {
  __shared__ __align__(16) short smem[2 * 320 * 64];   // 80 KiB, 2 blocks/CU
  const int tid = threadIdx.x;
  const int lane = tid & 63, wv = tid >> 6;
  const int c = lane & 15, g = lane >> 4;

  // ---- block swizzle: id -> (xq, yq), 8 rows x 6 cols per 48-id group ----
  const int mt = gridDim.y;
  int id = blockIdx.y * 6 + blockIdx.x;
  int mt8 = mt & ~7;
  int xq, yq;
  if (id < 6 * mt8) {
    int q = id / 48, r = id - q * 48;
    yq = q * 8 + (r & 7);
    xq = r >> 3;
  } else {
    int rem = id - 6 * mt8;
    xq = rem % 6;
    yq = mt8 + rem / 6;
  }
  const int n0 = xq * 192;
  const int row0 = yq * 128;

  f32x4 acc[8][3];
  const f32x4 zero = {0.f, 0.f, 0.f, 0.f};
#pragma unroll
  for (int m = 0; m < 8; m++)
#pragma unroll
    for (int nn = 0; nn < 3; nn++) acc[m][nn] = zero;

  const int rsub = lane >> 3;
  const int tchk = lane & 7;                         // logical A-chunk
  const int chnkB = ((lane & 7) ^ rsub) * 8;         // B: pre-swizzled source

  // A: per-lane f32 source (logical chunk, coalesced 32B) + swizzled LDS dest
  const float* aF[4];
  int aoff[4];
#pragma unroll
  for (int i = 0; i < 4; i++) {
    int r = (wv * 4 + i) * 8 + rsub;
    int grow = row0 + r;
    if (grow >= ntok) grow = ntok - 1;
    aF[i] = xf + (size_t)grow * 384 + tchk * 8;
    aoff[i] = r * 64 + ((tchk ^ rsub) * 8);
  }
  const short* bS[6];
#pragma unroll
  for (int j = 0; j < 6; j++) {
    int r = (wv * 6 + j) * 8 + rsub;
    bS[j] = Wqkv + (size_t)(n0 + r) * 384 + chnkB;
  }

  float4 a0[4], a1[4];
  auto loadA = [&](int ks) {
#pragma unroll
    for (int i = 0; i < 4; i++) {
      a0[i] = *(const float4*)(aF[i] + ks * 64);
      a1[i] = *(const float4*)(aF[i] + ks * 64 + 4);
    }
  };
  auto writeA = [&](int buf) {
    short* Asl = smem + buf * (320 * 64);
#pragma unroll
    for (int i = 0; i < 4; i++) {
      bf16x8 cv;
      cv[0] = f2bf(a0[i].x); cv[1] = f2bf(a0[i].y);
      cv[2] = f2bf(a0[i].z); cv[3] = f2bf(a0[i].w);
      cv[4] = f2bf(a1[i].x); cv[5] = f2bf(a1[i].y);
      cv[6] = f2bf(a1[i].z); cv[7] = f2bf(a1[i].w);
      *(bf16x8*)&Asl[aoff[i]] = cv;
    }
  };
  auto stageB = [&](int buf, int ks) {
    short* Bsl = smem + buf * (320 * 64) + 128 * 64;
#pragma unroll
    for (int j = 0; j < 6; j++)
      gl_lds16(bS[j] + ks * 64, Bsl + (wv * 6 + j) * 512);
  };

  loadA(0);
  stageB(0, 0);
  writeA(0);              // waits only its own loads (compiler vmcnt)
  __syncthreads();        // B(0) + A(0) visible
#pragma unroll
  for (int ks = 0; ks < 6; ks++) {
    const int cur = ks & 1;
    if (ks < 5) {
      loadA(ks + 1);      // f32 loads in flight across the MFMA block
      stageB(cur ^ 1, ks + 1);
    }
    const short* Asl = smem + cur * (320 * 64);
    const short* Bsl = Asl + 128 * 64;
#pragma unroll
    for (int kk = 0; kk < 2; kk++) {
      bf16x8 af[8];
#pragma unroll
      for (int m = 0; m < 8; m++) {
        int row = m * 16 + c;
        af[m] = *(const bf16x8*)&Asl[row * 64 + (((kk * 4 + g) ^ (row & 7)) * 8)];
      }
#pragma unroll
      for (int nn = 0; nn < 3; nn++) {
        int row = wv * 48 + nn * 16 + c;
        bf16x8 bfr = *(const bf16x8*)&Bsl[row * 64 + (((kk * 4 + g) ^ (row & 7)) * 8)];
#pragma unroll
        for (int m = 0; m < 8; m++) acc[m][nn] = MFMA16(af[m], bfr, acc[m][nn]);
      }
    }
    if (ks < 5) writeA(cur ^ 1);   // cvt + ds_write into the idle buffer
    __syncthreads();               // next tile (A writes + B gl_lds) ready
  }

  // epilogue in two 64-row halves through LDS, scatter to [bw][h][n][32]
  const int s = n0 / 384;
  short* base = (s == 0) ? qws : ((s == 1) ? kws : vws);
  const int hbase = (n0 - s * 384) >> 5;
#pragma unroll
  for (int half = 0; half < 2; half++) {
    __syncthreads();
#pragma unroll
    for (int nn = 0; nn < 3; nn++) {
      int colRel = wv * 48 + nn * 16 + c;
      float bias = bqkv[n0 + colRel];
#pragma unroll
      for (int mm = 0; mm < 4; mm++) {
        int m = half * 4 + mm;
#pragma unroll
        for (int r = 0; r < 4; r++)
          smem[(mm * 16 + g * 4 + r) * 200 + colRel] = f2bf(acc[m][nn][r] + bias);
      }
    }
    __syncthreads();
    for (int u = tid; u < 384; u += 256) {
      int row = u & 63, j = u >> 6;
      int tr = row0 + half * 64 + row;
      if (tr < ntok) {
        int bw = tr / 49;
        int n = tr - bw * 49;
        short* dst = base + ((size_t)(bw * 12 + hbase + j) * 49 + n) * 32;
        const uint4* src = (const uint4*)&smem[row * 200 + j * 32];
        uint4* d4 = (uint4*)dst;
        d4[0] = src[0]; d4[1] = src[1]; d4[2] = src[2]; d4[3] = src[3];
      }
    }
  }
}

// ---------------------------------------------------------------------------
// K2: attention, SWAPPED QK^T: St[m][n] = mfma(K,Q) puts a q-row's k-values
// lane-local (16/lane, 4 g-groups) -> softmax = in-reg tree + 2 shfl_xor
// (16,32) per m, vs 8 shfl per row before. P written as 16 ds_write_b64
// (normalized in-lane). Bias bmT pre-baked in this fragment layout. PV and
// O unchanged. V prefetched upfront (T14). setprio around MFMA (T5).
// ---------------------------------------------------------------------------
__global__ __launch_bounds__(256) void attn_kernel(
    const short* __restrict__ qws, const short* __restrict__ kws,
    const short* __restrict__ vws, short* __restrict__ ows,
    const float* __restrict__ bm, int b0, int nwmask) {
  __shared__ short Pall[4 * 64 * 72];
  const int tid = threadIdx.x;
  const int lane = tid & 63, wvi = tid >> 6;
  const int c = lane & 15, g = lane >> 4;
  const int task = blockIdx.x * 4 + wvi;   // grid = 3*nw blocks -> 12*nw tasks
  const int b = task / 12, h = task - b * 12;
  const int wm = (b0 + b) % nwmask;
  const short* qb = qws + (size_t)(b * 12 + h) * 1568;
  const short* kb = kws + (size_t)(b * 12 + h) * 1568;
  const short* vb = vws + (size_t)(b * 12 + h) * 1568;

  bf16x8 qf[4], kf[4];
#pragma unroll
  for (int m = 0; m < 4; m++) { int i = m * 16 + c; if (i > 48) i = 48; qf[m] = *(const bf16x8*)(qb + i * 32 + g * 8); }
#pragma unroll
  for (int n = 0; n < 4; n++) { int j = n * 16 + c; if (j > 48) j = 48; kf[n] = *(const bf16x8*)(kb + j * 32 + g * 8); }

  // V prefetch: independent until PV -> latency hidden under QK^T+softmax.
  bf16x8 vfr[2][2];
#pragma unroll
  for (int kk = 0; kk < 2; kk++)
#pragma unroll
    for (int dt = 0; dt < 2; dt++) {
      bf16x8 vf;
#pragma unroll
      for (int rr = 0; rr < 8; rr++) {
        int j = kk * 32 + g * 8 + rr; if (j > 48) j = 48;   // P[j>=49]==0
        vf[rr] = vb[j * 32 + dt * 16 + c];
      }
      vfr[kk][dt] = vf;
    }

  const f32x4 zero = {0.f, 0.f, 0.f, 0.f};
  // St[m][n][r] at lane (c,g) = S[q=m*16+c][k=n*16+g*4+r]
  f32x4 S[4][4];
  __builtin_amdgcn_s_setprio(1);
#pragma unroll
  for (int m = 0; m < 4; m++)
#pragma unroll
    for (int n = 0; n < 4; n++) S[m][n] = MFMA16(kf[n], qf[m], zero);
  __builtin_amdgcn_s_setprio(0);

  // bias+mask (bmT layout matches): one f32x4 per (m,n)
  const float* bmh = bm + (size_t)(wm * 12 + h) * 4096;
#pragma unroll
  for (int m = 0; m < 4; m++)
#pragma unroll
    for (int n = 0; n < 4; n++) {
      f32x4 b4 = *(const f32x4*)(bmh + ((m * 4 + n) * 16 + c) * 16 + g * 4);
      S[m][n][0] += b4[0]; S[m][n][1] += b4[1];
      S[m][n][2] += b4[2]; S[m][n][3] += b4[3];
    }

  // softmax: per m, q-row = m*16+c; 16 in-lane values + cross-g reduce
  short* P = Pall + wvi * 4608;
#pragma unroll
  for (int m = 0; m < 4; m++) {
    float mx = fmaxf(
        fmaxf(fmaxf(fmaxf(S[m][0][0], S[m][0][1]), fmaxf(S[m][0][2], S[m][0][3])),
              fmaxf(fmaxf(S[m][1][0], S[m][1][1]), fmaxf(S[m][1][2], S[m][1][3]))),
        fmaxf(fmaxf(fmaxf(S[m][2][0], S[m][2][1]), fmaxf(S[m][2][2], S[m][2][3])),
              fmaxf(fmaxf(S[m][3][0], S[m][3][1]), fmaxf(S[m][3][2], S[m][3][3]))));
    mx = fmaxf(mx, __shfl_xor(mx, 16));
    mx = fmaxf(mx, __shfl_xor(mx, 32));
    float e[4][4];
    float sm = 0.f;
#pragma unroll
    for (int n = 0; n < 4; n++)
#pragma unroll
      for (int r = 0; r < 4; r++) { e[n][r] = __expf(S[m][n][r] - mx); sm += e[n][r]; }
    sm += __shfl_xor(sm, 16);
    sm += __shfl_xor(sm, 32);
    float rv = 1.0f / sm;
#pragma unroll
    for (int n = 0; n < 4; n++) {
      uint32_t w0 = (uint32_t)(uint16_t)f2bf(e[n][0] * rv) |
                    ((uint32_t)(uint16_t)f2bf(e[n][1] * rv) << 16);
      uint32_t w1 = (uint32_t)(uint16_t)f2bf(e[n][2] * rv) |
                    ((uint32_t)(uint16_t)f2bf(e[n][3] * rv) << 16);
      uint2 w; w.x = w0; w.y = w1;
      *(uint2*)&P[(m * 16 + c) * 72 + n * 16 + g * 4] = w;   // P[q][k], b64
    }
  }
  // P is wave-private: same-wave LDS RAW ordered by lgkmcnt waits.

  f32x4 O[4][2];
#pragma unroll
  for (int m = 0; m < 4; m++) { O[m][0] = zero; O[m][1] = zero; }
#pragma unroll
  for (int kk = 0; kk < 2; kk++) {
    bf16x8 pf[4];
#pragma unroll
    for (int m = 0; m < 4; m++) pf[m] = *(const bf16x8*)&P[(m * 16 + c) * 72 + kk * 32 + g * 8];
    __builtin_amdgcn_s_setprio(1);
#pragma unroll
    for (int dt = 0; dt < 2; dt++)
#pragma unroll
      for (int m = 0; m < 4; m++) O[m][dt] = MFMA16(pf[m], vfr[kk][dt], O[m][dt]);
    __builtin_amdgcn_s_setprio(0);
  }
#pragma unroll
  for (int m = 0; m < 4; m++)
#pragma unroll
    for (int r = 0; r < 4; r++) {
      int i = m * 16 + g * 4 + r;
      if (i < 49) {
        size_t o = ((size_t)b * 49 + i) * 384 + h * 32;
        ows[o + c]      = f2bf(O[m][0][r]);
        ows[o + 16 + c] = f2bf(O[m][1][r]);
      }
    }
}

// ---------------------------------------------------------------------------
// K3: out = O @ Wp.T + bp ; tile 128x192 (x-blocks=2), counted-vmcnt 2-phase
// pipeline; NEW: epilogue through LDS (float view) -> coalesced float4 stores
// (was 96 scalar f32 stores/thread).
// ---------------------------------------------------------------------------
__global__ __launch_bounds__(256) void proj_gemm(
    const short* __restrict__ ows, const short* __restrict__ Wpb,
    const float* __restrict__ bpb, float* __restrict__ out,
    long tok0, int ntok) {
  __shared__ __align__(16) short smem[2 * 320 * 64];
  const int tid = threadIdx.x;
  const int lane = tid & 63, wv = tid >> 6;
  const int c = lane & 15, g = lane >> 4;

  // block swizzle: 8 rows x 2 cols per 16-id group
  const int mt = gridDim.y;
  int id = blockIdx.y * 2 + blockIdx.x;
  int mt8 = mt & ~7;
  int xq, yq;
  if (id < 2 * mt8) {
    int q = id / 16, r = id - q * 16;
    yq = q * 8 + (r & 7);
    xq = r >> 3;
  } else {
    int rem = id - 2 * mt8;
    xq = rem % 2;
    yq = mt8 + rem / 2;
  }
  const int n0 = xq * 192;
  const int row0 = yq * 128;

  f32x4 acc[8][3];
  const f32x4 zero = {0.f, 0.f, 0.f, 0.f};
#pragma unroll
  for (int m = 0; m < 8; m++)
#pragma unroll
    for (int nn = 0; nn < 3; nn++) acc[m][nn] = zero;

  const int rsub = lane >> 3;
  const int chnk = ((lane & 7) ^ rsub) * 8;
  const short* aS[4];
  const short* bS[6];
#pragma unroll
  for (int i = 0; i < 4; i++) {
    int r = (wv * 4 + i) * 8 + rsub;
    int grow = row0 + r;
    if (grow >= ntok) grow = ntok - 1;
    aS[i] = ows + (size_t)grow * 384 + chnk;
  }
#pragma unroll
  for (int j = 0; j < 6; j++) {
    int r = (wv * 6 + j) * 8 + rsub;
    bS[j] = Wpb + (size_t)(n0 + r) * 384 + chnk;
  }

  auto stage = [&](int buf, int ks) {
    short* Asl = smem + buf * (320 * 64);
    short* Bsl = Asl + 128 * 64;
#pragma unroll
    for (int i = 0; i < 4; i++)
      gl_lds16(aS[i] + ks * 64, Asl + (wv * 4 + i) * 512);
#pragma unroll
    for (int j = 0; j < 6; j++)
      gl_lds16(bS[j] + ks * 64, Bsl + (wv * 6 + j) * 512);
  };

  stage(0, 0);
  asm volatile("s_waitcnt vmcnt(0)" ::: "memory");
  __builtin_amdgcn_s_barrier();
#pragma unroll
  for (int ks = 0; ks < 6; ks++) {
    const int cur = ks & 1;
    if (ks < 5) {
      stage(cur ^ 1, ks + 1);
      asm volatile("s_waitcnt vmcnt(10)" ::: "memory");
    } else {
      asm volatile("s_waitcnt vmcnt(0)" ::: "memory");
    }
    __builtin_amdgcn_sched_barrier(0);
    __builtin_amdgcn_s_barrier();
    const short* Asl = smem + cur * (320 * 64);
    const short* Bsl = Asl + 128 * 64;
#pragma unroll
    for (int kk = 0; kk < 2; kk++) {
      bf16x8 af[8];
#pragma unroll
      for (int m = 0; m < 8; m++) {
        int row = m * 16 + c;
        af[m] = *(const bf16x8*)&Asl[row * 64 + (((kk * 4 + g) ^ (row & 7)) * 8)];
      }
#pragma unroll
      for (int nn = 0; nn < 3; nn++) {
        int row = wv * 48 + nn * 16 + c;
        bf16x8 bfr = *(const bf16x8*)&Bsl[row * 64 + (((kk * 4 + g) ^ (row & 7)) * 8)];
#pragma unroll
        for (int m = 0; m < 8; m++) acc[m][nn] = MFMA16(af[m], bfr, acc[m][nn]);
      }
    }
    __builtin_amdgcn_sched_barrier(0);
    __builtin_amdgcn_s_barrier();
  }

  // epilogue: LDS transpose (float view, stride 196) -> coalesced float4
  float* fs = (float*)smem;   // 64 x 196 f32 = 50176 B < 81920 B
#pragma unroll
  for (int half = 0; half < 2; half++) {
    __syncthreads();
#pragma unroll
    for (int nn = 0; nn < 3; nn++) {
      int colRel = wv * 48 + nn * 16 + c;
      float bias = bpb[n0 + colRel];
#pragma unroll
      for (int mm = 0; mm < 4; mm++) {
        int m = half * 4 + mm;
#pragma unroll
        for (int r = 0; r < 4; r++)
          fs[(mm * 16 + g * 4 + r) * 196 + colRel] = acc[m][nn][r] + bias;
      }
    }
    __syncthreads();
#pragma unroll
    for (int t = 0; t < 12; t++) {
      int v = tid + t * 256;              // 64 rows x 48 float4
      int row = v / 48, c4 = v - row * 48;
      int tr = row0 + half * 64 + row;
      if (tr < ntok)
        *(float4*)&out[(size_t)(tok0 + tr) * 384 + n0 + c4 * 4] =
            *(const float4*)&fs[row * 196 + c4 * 4];
    }
  }
}

// ---------------------------------------------------------------------------
extern "C" void kernel_launch(void* const* d_in, const int* in_sizes, int n_in,
                              void* d_out, int out_size, void* d_ws, size_t ws_size,
                              hipStream_t stream) {
  const float* x    = (const float*)d_in[0];
  const float* mask = (const float*)d_in[1];
  const float* Wq = (const float*)d_in[2];
  const float* bq = (const float*)d_in[3];
  const float* Wk = (const float*)d_in[4];
  const float* bk = (const float*)d_in[5];
  const float* Wv = (const float*)d_in[6];
  const float* bv = (const float*)d_in[7];
  const float* Wp = (const float*)d_in[8];
  const float* bp = (const float*)d_in[9];
  const float* table = (const float*)d_in[10];
  float* out = (float*)d_out;

  const int Btot = in_sizes[0] / (49 * 384);   // 2048
  const int NWm  = in_sizes[1] / (49 * 49);    // 64

  char* ws = (char*)d_ws;
  short* Wqkv = (short*)ws;                     // 1152*384 bf16
  short* Wpb  = Wqkv + 1152 * 384;              // 384*384 bf16
  float* bqkv = (float*)(Wpb + 384 * 384);      // 1152 f32
  float* bpb  = bqkv + 1152;                    // 384 f32
  float* bmp  = bpb + 384;                      // NWm*12*4096 f32 (swapped C-layout)
  size_t fixedB = (size_t)(1152 * 384 + 384 * 384) * 2 + (1152 + 384) * 4
                + (size_t)NWm * 12 * 4096 * 4;
  char* dyn = ws + ((fixedB + 255) & ~(size_t)255);
  size_t used = (size_t)(dyn - ws);
  size_t avail = (ws_size > used + 4096) ? (ws_size - used - 4096) : 0;
  const size_t perw = (size_t)4 * 18816 * 2;    // q,k,v,O bf16 per window
  long nwc = (long)(avail / perw);
  if (nwc > Btot) nwc = Btot;
  if (nwc >= 64) nwc &= ~63L;
  if (nwc < 1) nwc = 1;
  short* qws = (short*)dyn;
  short* kws = qws + (size_t)nwc * 18816;
  short* vws = kws + (size_t)nwc * 18816;
  short* ows = vws + (size_t)nwc * 18816;

  prep_w<<<dim3(1728), dim3(256), 0, stream>>>(Wq, bq, Wk, bk, Wv, bv, Wp, bp,
                                               Wqkv, Wpb, bqkv, bpb);
  prep_bm<<<dim3(NWm * 12), dim3(256), 0, stream>>>(table, mask, bmp, NWm);

  for (long b0 = 0; b0 < Btot; b0 += nwc) {
    int nw = (int)((Btot - b0 < nwc) ? (Btot - b0) : nwc);
    int ntok = nw * 49;
    long tok0 = b0 * 49;
    int mt = (ntok + 127) / 128;
    qkv_gemm<<<dim3(6, mt), dim3(256), 0, stream>>>(x + tok0 * 384, Wqkv, bqkv,
                                                    qws, kws, vws, ntok);
    attn_kernel<<<dim3(3 * nw), dim3(256), 0, stream>>>(qws, kws, vws, ows, bmp,
                                                        (int)b0, NWm);
    proj_gemm<<<dim3(2, mt), dim3(256), 0, stream>>>(ows, Wpb, bpb, out, tok0, ntok);
  }
}

// Round 7
// 543.812 us; speedup vs baseline: 1.2216x; 1.0490x over previous
//
#include <hip/hip_runtime.h>
#include <stdint.h>

using bf16x8 = __attribute__((ext_vector_type(8))) short;
using f32x4  = __attribute__((ext_vector_type(4))) float;

__device__ __forceinline__ short f2bf(float f) {
  uint32_t u = __float_as_uint(f);
  u += 0x7fff + ((u >> 16) & 1u);
  return (short)(u >> 16);
}

#define MFMA16(a, b, c) __builtin_amdgcn_mfma_f32_16x16x32_bf16((a), (b), (c), 0, 0, 0)

// async global->LDS, 16B per lane; LDS dest is wave-uniform base + lane*16
__device__ __forceinline__ void gl_lds16(const short* g, short* l) {
  __builtin_amdgcn_global_load_lds(
      (const __attribute__((address_space(1))) void*)g,
      (__attribute__((address_space(3))) void*)l, 16, 0, 0);
}

// ---------------------------------------------------------------------------
// prep_w: pack Wq*scale|Wk|Wv -> bf16 [1152][384], Wp -> bf16, biases fp32
// ---------------------------------------------------------------------------
__global__ void prep_w(const float* __restrict__ Wq, const float* __restrict__ bq,
                       const float* __restrict__ Wk, const float* __restrict__ bk,
                       const float* __restrict__ Wv, const float* __restrict__ bv,
                       const float* __restrict__ Wp, const float* __restrict__ bp,
                       short* __restrict__ Wqkv, short* __restrict__ Wpb,
                       float* __restrict__ bqkv, float* __restrict__ bpb) {
  int i = blockIdx.x * 256 + threadIdx.x;
  const float scale = 0.17677669529663687f;  // 32^-0.5, folded into q
  if (i < 1152 * 384) {
    int r = i / 384, k = i - r * 384;
    float v;
    if (r < 384)      v = Wq[r * 384 + k] * scale;
    else if (r < 768) v = Wk[(r - 384) * 384 + k];
    else              v = Wv[(r - 768) * 384 + k];
    Wqkv[i] = f2bf(v);
  }
  if (i < 384 * 384) Wpb[i] = f2bf(Wp[i]);
  if (i < 1152) bqkv[i] = (i < 384) ? bq[i] * scale : ((i < 768) ? bk[i - 384] : bv[i - 768]);
  if (i < 384) bpb[i] = bp[i];
}

// ---------------------------------------------------------------------------
// prep_bm: bias+mask baked in the SWAPPED-QK^T C-fragment layout.
// bmT[wm][h][mn(16)][c(16)][i(16)] = bias(row_q=(mn>>2)*16+c, col_k=(mn&3)*16+i)
// pad rows/cols (>=49) -> -3e38 (finite: avoids inf-inf NaN; exp -> 0).
// ---------------------------------------------------------------------------
__global__ void prep_bm(const float* __restrict__ table, const float* __restrict__ mask,
                        float* __restrict__ bmT, int nwmask) {
  int wm = blockIdx.x / 12, h = blockIdx.x - wm * 12;
  const float* mrow = mask + (size_t)wm * 2401;
  float* dst = bmT + (size_t)blockIdx.x * 4096;
  for (int e = threadIdx.x; e < 4096; e += 256) {
    int mn = e >> 8, cf = (e >> 4) & 15, if_ = e & 15;
    int row = (mn >> 2) * 16 + cf;   // q-row from c-field (swapped layout)
    int col = (mn & 3) * 16 + if_;   // k-col from i-field
    float v = -3.0e38f;
    if (row < 49 && col < 49) {
      int id = row / 7, ir = row - id * 7;
      int jd = col / 7, jr = col - jd * 7;
      int idx = (id - jd + 6) * 13 + (ir - jr + 6);
      v = table[idx * 12 + h] + mrow[row * 49 + col];
    }
    dst[e] = v;
  }
}

// ---------------------------------------------------------------------------
// prep_x: fp32 -> bf16 conversion of a chunk of x (8 elements / thread)
// (round-6 fusion into qkv was -106us in qkv vs -60us saved: unbundled back)
// ---------------------------------------------------------------------------
__global__ void prep_x(const float* __restrict__ x, short* __restrict__ xb, int n8) {
  int u = blockIdx.x * 256 + threadIdx.x;
  if (u < n8) {
    int e = u * 8;
    float4 f0 = *(const float4*)(x + e);
    float4 f1 = *(const float4*)(x + e + 4);
    bf16x8 cv;
    cv[0] = f2bf(f0.x); cv[1] = f2bf(f0.y); cv[2] = f2bf(f0.z); cv[3] = f2bf(f0.w);
    cv[4] = f2bf(f1.x); cv[5] = f2bf(f1.y); cv[6] = f2bf(f1.z); cv[7] = f2bf(f1.w);
    *(bf16x8*)(xb + e) = cv;
  }
}

// ---------------------------------------------------------------------------
// K1: qkv = xb @ Wqkv.T + bqkv ; writes q,k,v bf16 in [bw][h][n][32] layout
// tile 128(M) x 192(N), 4 waves, BK=64, 2-phase dbuf with COUNTED vmcnt
// (round-5 proven: 148.5us, MfmaUtil 25, 0 bank conflicts).
// ---------------------------------------------------------------------------
__global__ __launch_bounds__(256) void qkv_gemm(
    const short* __restrict__ xb, const short* __restrict__ Wqkv,
    const float* __restrict__ bqkv,
    short* __restrict__ qws, short* __restrict__ kws, short* __restrict__ vws,
    int ntok) {
  // two buffers: each buf = As[128][64] | Bs[192][64] = 320*64 shorts
  __shared__ __align__(16) short smem[2 * 320 * 64];   // 80 KiB -> 2 blocks/CU
  const int tid = threadIdx.x;
  const int lane = tid & 63, wv = tid >> 6;
  const int c = lane & 15, g = lane >> 4;

  // ---- block swizzle: id -> (xq, yq), 8 rows x 6 cols per 48-id group ----
  const int mt = gridDim.y;
  int id = blockIdx.y * 6 + blockIdx.x;
  int mt8 = mt & ~7;
  int xq, yq;
  if (id < 6 * mt8) {
    int q = id / 48, r = id - q * 48;
    yq = q * 8 + (r & 7);
    xq = r >> 3;
  } else {
    int rem = id - 6 * mt8;
    xq = rem % 6;
    yq = mt8 + rem / 6;
  }
  const int n0 = xq * 192;
  const int row0 = yq * 128;

  f32x4 acc[8][3];
  const f32x4 zero = {0.f, 0.f, 0.f, 0.f};
#pragma unroll
  for (int m = 0; m < 8; m++)
#pragma unroll
    for (int nn = 0; nn < 3; nn++) acc[m][nn] = zero;

  // per-lane source swizzle: lane covers (row r0+(lane>>3), chunk lane&7);
  // logical chunk = (lane&7) ^ (r&7) with r&7 == lane>>3
  const int rsub = lane >> 3;
  const int chnk = ((lane & 7) ^ rsub) * 8;  // short offset within a 64-elt row
  const short* aS[4];
  const short* bS[6];
#pragma unroll
  for (int i = 0; i < 4; i++) {
    int r = (wv * 4 + i) * 8 + rsub;
    int grow = row0 + r;
    if (grow >= ntok) grow = ntok - 1;
    aS[i] = xb + (size_t)grow * 384 + chnk;
  }
#pragma unroll
  for (int j = 0; j < 6; j++) {
    int r = (wv * 6 + j) * 8 + rsub;
    bS[j] = Wqkv + (size_t)(n0 + r) * 384 + chnk;
  }

  auto stage = [&](int buf, int ks) {
    short* Asl = smem + buf * (320 * 64);
    short* Bsl = Asl + 128 * 64;
#pragma unroll
    for (int i = 0; i < 4; i++)
      gl_lds16(aS[i] + ks * 64, Asl + (wv * 4 + i) * 512);
#pragma unroll
    for (int j = 0; j < 6; j++)
      gl_lds16(bS[j] + ks * 64, Bsl + (wv * 6 + j) * 512);
  };

  stage(0, 0);
  asm volatile("s_waitcnt vmcnt(0)" ::: "memory");
  __builtin_amdgcn_s_barrier();            // tile 0 resident for all waves
#pragma unroll
  for (int ks = 0; ks < 6; ks++) {
    const int cur = ks & 1;
    if (ks < 5) {
      stage(cur ^ 1, ks + 1);              // +10 loads, stay in flight
      asm volatile("s_waitcnt vmcnt(10)" ::: "memory");  // oldest 10 (= cur) done
    } else {
      asm volatile("s_waitcnt vmcnt(0)" ::: "memory");
    }
    __builtin_amdgcn_sched_barrier(0);     // rule 18: pin waitcnt before barrier
    __builtin_amdgcn_s_barrier();          // all waves' cur loads done
    const short* Asl = smem + cur * (320 * 64);
    const short* Bsl = Asl + 128 * 64;
#pragma unroll
    for (int kk = 0; kk < 2; kk++) {
      bf16x8 af[8];
#pragma unroll
      for (int m = 0; m < 8; m++) {
        int row = m * 16 + c;
        af[m] = *(const bf16x8*)&Asl[row * 64 + (((kk * 4 + g) ^ (row & 7)) * 8)];
      }
#pragma unroll
      for (int nn = 0; nn < 3; nn++) {
        int row = wv * 48 + nn * 16 + c;
        bf16x8 bfr = *(const bf16x8*)&Bsl[row * 64 + (((kk * 4 + g) ^ (row & 7)) * 8)];
#pragma unroll
        for (int m = 0; m < 8; m++) acc[m][nn] = MFMA16(af[m], bfr, acc[m][nn]);
      }
    }
    __builtin_amdgcn_sched_barrier(0);
    __builtin_amdgcn_s_barrier();          // readers of cur done before re-stage
  }

  // epilogue in two 64-row halves through LDS, scatter to [bw][h][n][32]
  const int s = n0 / 384;
  short* base = (s == 0) ? qws : ((s == 1) ? kws : vws);
  const int hbase = (n0 - s * 384) >> 5;
#pragma unroll
  for (int half = 0; half < 2; half++) {
    __syncthreads();
#pragma unroll
    for (int nn = 0; nn < 3; nn++) {
      int colRel = wv * 48 + nn * 16 + c;
      float bias = bqkv[n0 + colRel];
#pragma unroll
      for (int mm = 0; mm < 4; mm++) {
        int m = half * 4 + mm;
#pragma unroll
        for (int r = 0; r < 4; r++)
          smem[(mm * 16 + g * 4 + r) * 200 + colRel] = f2bf(acc[m][nn][r] + bias);
      }
    }
    __syncthreads();
    for (int u = tid; u < 384; u += 256) {
      int row = u & 63, j = u >> 6;
      int tr = row0 + half * 64 + row;
      if (tr < ntok) {
        int bw = tr / 49;
        int n = tr - bw * 49;
        short* dst = base + ((size_t)(bw * 12 + hbase + j) * 49 + n) * 32;
        const uint4* src = (const uint4*)&smem[row * 200 + j * 32];
        uint4* d4 = (uint4*)dst;
        d4[0] = src[0]; d4[1] = src[1]; d4[2] = src[2]; d4[3] = src[3];
      }
    }
  }
}

// ---------------------------------------------------------------------------
// K2: attention, SWAPPED QK^T: St[m][n] = mfma(K,Q) puts a q-row's k-values
// lane-local (16/lane, 4 g-groups) -> softmax = in-reg tree + 2 shfl_xor
// (16,32) per m. P written as 16 ds_write_b64 (normalized in-lane). Bias
// bmT pre-baked in this fragment layout. V prefetched upfront (T14).
// setprio around MFMA (T5).
// ---------------------------------------------------------------------------
__global__ __launch_bounds__(256) void attn_kernel(
    const short* __restrict__ qws, const short* __restrict__ kws,
    const short* __restrict__ vws, short* __restrict__ ows,
    const float* __restrict__ bm, int b0, int nwmask) {
  __shared__ short Pall[4 * 64 * 72];
  const int tid = threadIdx.x;
  const int lane = tid & 63, wvi = tid >> 6;
  const int c = lane & 15, g = lane >> 4;
  const int task = blockIdx.x * 4 + wvi;   // grid = 3*nw blocks -> 12*nw tasks
  const int b = task / 12, h = task - b * 12;
  const int wm = (b0 + b) % nwmask;
  const short* qb = qws + (size_t)(b * 12 + h) * 1568;
  const short* kb = kws + (size_t)(b * 12 + h) * 1568;
  const short* vb = vws + (size_t)(b * 12 + h) * 1568;

  bf16x8 qf[4], kf[4];
#pragma unroll
  for (int m = 0; m < 4; m++) { int i = m * 16 + c; if (i > 48) i = 48; qf[m] = *(const bf16x8*)(qb + i * 32 + g * 8); }
#pragma unroll
  for (int n = 0; n < 4; n++) { int j = n * 16 + c; if (j > 48) j = 48; kf[n] = *(const bf16x8*)(kb + j * 32 + g * 8); }

  // V prefetch: independent until PV -> latency hidden under QK^T+softmax.
  bf16x8 vfr[2][2];
#pragma unroll
  for (int kk = 0; kk < 2; kk++)
#pragma unroll
    for (int dt = 0; dt < 2; dt++) {
      bf16x8 vf;
#pragma unroll
      for (int rr = 0; rr < 8; rr++) {
        int j = kk * 32 + g * 8 + rr; if (j > 48) j = 48;   // P[j>=49]==0
        vf[rr] = vb[j * 32 + dt * 16 + c];
      }
      vfr[kk][dt] = vf;
    }

  const f32x4 zero = {0.f, 0.f, 0.f, 0.f};
  // St[m][n][r] at lane (c,g) = S[q=m*16+c][k=n*16+g*4+r]
  f32x4 S[4][4];
  __builtin_amdgcn_s_setprio(1);
#pragma unroll
  for (int m = 0; m < 4; m++)
#pragma unroll
    for (int n = 0; n < 4; n++) S[m][n] = MFMA16(kf[n], qf[m], zero);
  __builtin_amdgcn_s_setprio(0);

  // bias+mask (bmT layout matches): one f32x4 per (m,n)
  const float* bmh = bm + (size_t)(wm * 12 + h) * 4096;
#pragma unroll
  for (int m = 0; m < 4; m++)
#pragma unroll
    for (int n = 0; n < 4; n++) {
      f32x4 b4 = *(const f32x4*)(bmh + ((m * 4 + n) * 16 + c) * 16 + g * 4);
      S[m][n][0] += b4[0]; S[m][n][1] += b4[1];
      S[m][n][2] += b4[2]; S[m][n][3] += b4[3];
    }

  // softmax: per m, q-row = m*16+c; 16 in-lane values + cross-g reduce
  short* P = Pall + wvi * 4608;
#pragma unroll
  for (int m = 0; m < 4; m++) {
    float mx = fmaxf(
        fmaxf(fmaxf(fmaxf(S[m][0][0], S[m][0][1]), fmaxf(S[m][0][2], S[m][0][3])),
              fmaxf(fmaxf(S[m][1][0], S[m][1][1]), fmaxf(S[m][1][2], S[m][1][3]))),
        fmaxf(fmaxf(fmaxf(S[m][2][0], S[m][2][1]), fmaxf(S[m][2][2], S[m][2][3])),
              fmaxf(fmaxf(S[m][3][0], S[m][3][1]), fmaxf(S[m][3][2], S[m][3][3]))));
    mx = fmaxf(mx, __shfl_xor(mx, 16));
    mx = fmaxf(mx, __shfl_xor(mx, 32));
    float e[4][4];
    float sm = 0.f;
#pragma unroll
    for (int n = 0; n < 4; n++)
#pragma unroll
      for (int r = 0; r < 4; r++) { e[n][r] = __expf(S[m][n][r] - mx); sm += e[n][r]; }
    sm += __shfl_xor(sm, 16);
    sm += __shfl_xor(sm, 32);
    float rv = 1.0f / sm;
#pragma unroll
    for (int n = 0; n < 4; n++) {
      uint32_t w0 = (uint32_t)(uint16_t)f2bf(e[n][0] * rv) |
                    ((uint32_t)(uint16_t)f2bf(e[n][1] * rv) << 16);
      uint32_t w1 = (uint32_t)(uint16_t)f2bf(e[n][2] * rv) |
                    ((uint32_t)(uint16_t)f2bf(e[n][3] * rv) << 16);
      uint2 w; w.x = w0; w.y = w1;
      *(uint2*)&P[(m * 16 + c) * 72 + n * 16 + g * 4] = w;   // P[q][k], b64
    }
  }
  // P is wave-private: same-wave LDS RAW ordered by lgkmcnt waits.

  f32x4 O[4][2];
#pragma unroll
  for (int m = 0; m < 4; m++) { O[m][0] = zero; O[m][1] = zero; }
#pragma unroll
  for (int kk = 0; kk < 2; kk++) {
    bf16x8 pf[4];
#pragma unroll
    for (int m = 0; m < 4; m++) pf[m] = *(const bf16x8*)&P[(m * 16 + c) * 72 + kk * 32 + g * 8];
    __builtin_amdgcn_s_setprio(1);
#pragma unroll
    for (int dt = 0; dt < 2; dt++)
#pragma unroll
      for (int m = 0; m < 4; m++) O[m][dt] = MFMA16(pf[m], vfr[kk][dt], O[m][dt]);
    __builtin_amdgcn_s_setprio(0);
  }
#pragma unroll
  for (int m = 0; m < 4; m++)
#pragma unroll
    for (int r = 0; r < 4; r++) {
      int i = m * 16 + g * 4 + r;
      if (i < 49) {
        size_t o = ((size_t)b * 49 + i) * 384 + h * 32;
        ows[o + c]      = f2bf(O[m][0][r]);
        ows[o + 16 + c] = f2bf(O[m][1][r]);
      }
    }
}

// ---------------------------------------------------------------------------
// K3: out = O @ Wp.T + bp ; tile 128x192 (x-blocks=2), counted-vmcnt 2-phase
// pipeline; epilogue through LDS (float view) -> coalesced float4 stores.
// ---------------------------------------------------------------------------
__global__ __launch_bounds__(256) void proj_gemm(
    const short* __restrict__ ows, const short* __restrict__ Wpb,
    const float* __restrict__ bpb, float* __restrict__ out,
    long tok0, int ntok) {
  __shared__ __align__(16) short smem[2 * 320 * 64];
  const int tid = threadIdx.x;
  const int lane = tid & 63, wv = tid >> 6;
  const int c = lane & 15, g = lane >> 4;

  // block swizzle: 8 rows x 2 cols per 16-id group
  const int mt = gridDim.y;
  int id = blockIdx.y * 2 + blockIdx.x;
  int mt8 = mt & ~7;
  int xq, yq;
  if (id < 2 * mt8) {
    int q = id / 16, r = id - q * 16;
    yq = q * 8 + (r & 7);
    xq = r >> 3;
  } else {
    int rem = id - 2 * mt8;
    xq = rem % 2;
    yq = mt8 + rem / 2;
  }
  const int n0 = xq * 192;
  const int row0 = yq * 128;

  f32x4 acc[8][3];
  const f32x4 zero = {0.f, 0.f, 0.f, 0.f};
#pragma unroll
  for (int m = 0; m < 8; m++)
#pragma unroll
    for (int nn = 0; nn < 3; nn++) acc[m][nn] = zero;

  const int rsub = lane >> 3;
  const int chnk = ((lane & 7) ^ rsub) * 8;
  const short* aS[4];
  const short* bS[6];
#pragma unroll
  for (int i = 0; i < 4; i++) {
    int r = (wv * 4 + i) * 8 + rsub;
    int grow = row0 + r;
    if (grow >= ntok) grow = ntok - 1;
    aS[i] = ows + (size_t)grow * 384 + chnk;
  }
#pragma unroll
  for (int j = 0; j < 6; j++) {
    int r = (wv * 6 + j) * 8 + rsub;
    bS[j] = Wpb + (size_t)(n0 + r) * 384 + chnk;
  }

  auto stage = [&](int buf, int ks) {
    short* Asl = smem + buf * (320 * 64);
    short* Bsl = Asl + 128 * 64;
#pragma unroll
    for (int i = 0; i < 4; i++)
      gl_lds16(aS[i] + ks * 64, Asl + (wv * 4 + i) * 512);
#pragma unroll
    for (int j = 0; j < 6; j++)
      gl_lds16(bS[j] + ks * 64, Bsl + (wv * 6 + j) * 512);
  };

  stage(0, 0);
  asm volatile("s_waitcnt vmcnt(0)" ::: "memory");
  __builtin_amdgcn_s_barrier();
#pragma unroll
  for (int ks = 0; ks < 6; ks++) {
    const int cur = ks & 1;
    if (ks < 5) {
      stage(cur ^ 1, ks + 1);
      asm volatile("s_waitcnt vmcnt(10)" ::: "memory");
    } else {
      asm volatile("s_waitcnt vmcnt(0)" ::: "memory");
    }
    __builtin_amdgcn_sched_barrier(0);
    __builtin_amdgcn_s_barrier();
    const short* Asl = smem + cur * (320 * 64);
    const short* Bsl = Asl + 128 * 64;
#pragma unroll
    for (int kk = 0; kk < 2; kk++) {
      bf16x8 af[8];
#pragma unroll
      for (int m = 0; m < 8; m++) {
        int row = m * 16 + c;
        af[m] = *(const bf16x8*)&Asl[row * 64 + (((kk * 4 + g) ^ (row & 7)) * 8)];
      }
#pragma unroll
      for (int nn = 0; nn < 3; nn++) {
        int row = wv * 48 + nn * 16 + c;
        bf16x8 bfr = *(const bf16x8*)&Bsl[row * 64 + (((kk * 4 + g) ^ (row & 7)) * 8)];
#pragma unroll
        for (int m = 0; m < 8; m++) acc[m][nn] = MFMA16(af[m], bfr, acc[m][nn]);
      }
    }
    __builtin_amdgcn_sched_barrier(0);
    __builtin_amdgcn_s_barrier();
  }

  // epilogue: LDS transpose (float view, stride 196) -> coalesced float4
  float* fs = (float*)smem;   // 64 x 196 f32 = 50176 B < 81920 B
#pragma unroll
  for (int half = 0; half < 2; half++) {
    __syncthreads();
#pragma unroll
    for (int nn = 0; nn < 3; nn++) {
      int colRel = wv * 48 + nn * 16 + c;
      float bias = bpb[n0 + colRel];
#pragma unroll
      for (int mm = 0; mm < 4; mm++) {
        int m = half * 4 + mm;
#pragma unroll
        for (int r = 0; r < 4; r++)
          fs[(mm * 16 + g * 4 + r) * 196 + colRel] = acc[m][nn][r] + bias;
      }
    }
    __syncthreads();
#pragma unroll
    for (int t = 0; t < 12; t++) {
      int v = tid + t * 256;              // 64 rows x 48 float4
      int row = v / 48, c4 = v - row * 48;
      int tr = row0 + half * 64 + row;
      if (tr < ntok)
        *(float4*)&out[(size_t)(tok0 + tr) * 384 + n0 + c4 * 4] =
            *(const float4*)&fs[row * 196 + c4 * 4];
    }
  }
}

// ---------------------------------------------------------------------------
extern "C" void kernel_launch(void* const* d_in, const int* in_sizes, int n_in,
                              void* d_out, int out_size, void* d_ws, size_t ws_size,
                              hipStream_t stream) {
  const float* x    = (const float*)d_in[0];
  const float* mask = (const float*)d_in[1];
  const float* Wq = (const float*)d_in[2];
  const float* bq = (const float*)d_in[3];
  const float* Wk = (const float*)d_in[4];
  const float* bk = (const float*)d_in[5];
  const float* Wv = (const float*)d_in[6];
  const float* bv = (const float*)d_in[7];
  const float* Wp = (const float*)d_in[8];
  const float* bp = (const float*)d_in[9];
  const float* table = (const float*)d_in[10];
  float* out = (float*)d_out;

  const int Btot = in_sizes[0] / (49 * 384);   // 2048
  const int NWm  = in_sizes[1] / (49 * 49);    // 64

  char* ws = (char*)d_ws;
  short* Wqkv = (short*)ws;                     // 1152*384 bf16
  short* Wpb  = Wqkv + 1152 * 384;              // 384*384 bf16
  float* bqkv = (float*)(Wpb + 384 * 384);      // 1152 f32
  float* bpb  = bqkv + 1152;                    // 384 f32
  float* bmp  = bpb + 384;                      // NWm*12*4096 f32 (swapped C-layout)
  size_t fixedB = (size_t)(1152 * 384 + 384 * 384) * 2 + (1152 + 384) * 4
                + (size_t)NWm * 12 * 4096 * 4;
  char* dyn = ws + ((fixedB + 255) & ~(size_t)255);
  size_t used = (size_t)(dyn - ws);
  size_t avail = (ws_size > used + 4096) ? (ws_size - used - 4096) : 0;
  const size_t perw = (size_t)5 * 18816 * 2;    // xb,q,k,v,O bf16 per window
  long nwc = (long)(avail / perw);
  if (nwc > Btot) nwc = Btot;
  if (nwc >= 64) nwc &= ~63L;
  if (nwc < 1) nwc = 1;
  short* xbw = (short*)dyn;
  short* qws = xbw + (size_t)nwc * 18816;
  short* kws = qws + (size_t)nwc * 18816;
  short* vws = kws + (size_t)nwc * 18816;
  short* ows = vws + (size_t)nwc * 18816;

  prep_w<<<dim3(1728), dim3(256), 0, stream>>>(Wq, bq, Wk, bk, Wv, bv, Wp, bp,
                                               Wqkv, Wpb, bqkv, bpb);
  prep_bm<<<dim3(NWm * 12), dim3(256), 0, stream>>>(table, mask, bmp, NWm);

  for (long b0 = 0; b0 < Btot; b0 += nwc) {
    int nw = (int)((Btot - b0 < nwc) ? (Btot - b0) : nwc);
    int ntok = nw * 49;
    long tok0 = b0 * 49;
    int n8 = ntok * 48;  // ntok*384/8
    prep_x<<<dim3((n8 + 255) / 256), dim3(256), 0, stream>>>(x + tok0 * 384, xbw, n8);
    int mt = (ntok + 127) / 128;
    qkv_gemm<<<dim3(6, mt), dim3(256), 0, stream>>>(xbw, Wqkv, bqkv, qws, kws, vws, ntok);
    attn_kernel<<<dim3(3 * nw), dim3(256), 0, stream>>>(qws, kws, vws, ows, bmp,
                                                        (int)b0, NWm);
    proj_gemm<<<dim3(2, mt), dim3(256), 0, stream>>>(ows, Wpb, bpb, out, tok0, ntok);
  }
}